// Round 11
// baseline (287.361 us; speedup 1.0000x reference)
//
#include <hip/hip_runtime.h>
#include <hip/hip_bf16.h>

// ---------------------------------------------------------------------------
// EncoderBlock on MI355X (gfx950). Round 24.
// r23 post-mortem: gemm256 (coarse counted-vmcnt ring-2) for ffn1 = null --
// matches m196/m230 (without the fine 8-phase interleave, counted vmcnt
// buys ~nothing over 2-phase). r20's natural experiment bounds the pool:
// {oproj, ln1, ffn2, ln2} ~ 124 us -> oproj+ffn2 (gemm_bt64) ~ 112 us at
// ~190 TF: BM=64 = 8 MFMA/wave per drain, grid 512 = 2 blocks/CU (TLP too
// low to cover drains; resources allow 4). r24: SPLIT-K=2 for both ->
// grid (128,4,2) = 1024 blocks = 4 blocks/CU. Partials in f32: kp0(+bias)
// -> P1, kp1 -> P2; combined inside the LN kernels (lnsk reads residual +
// P1 + P2; LN input now f32 -- more accurate than old bf16 round-trip).
// oproj partials live in the idle ff1 region (32 MB, consumed by ln1
// before ffn1 overwrites); ffn2 partials in d_out + regA + regC.
//
// ws layout (bytes), WS_NEED = 73416704, sentinel-guarded:
//   [0,        2097152)  wq|wk|wv|wo T (bf16)
//   [2097152,  4194304)  w1T
//   [4194304,  6291456)  w2T
//   [6291456, 14680064)  xcv: x as bf16 (8 MB)
//   [14680064,14696448)  small params (bf16)
//   A [14696448,23085056) qbuf; then ffn2 partial P2 rows 0..4095 (f32)
//   B [23085056,31473664) kbuf -> y (bf16)
//   C [31473664,39862272) vT;   then ffn2 partial P2 rows 4096..8191 (f32)
//   F [39862272,73416704) oproj partials P1|P2 (2x16MB f32) -> ff1 (32 MB)
//   d_out                attn out (bf16) -> ffn2 partial P1 (f32) -> final
// ---------------------------------------------------------------------------

typedef __bf16 bf16;
typedef __bf16 bf16x4 __attribute__((ext_vector_type(4)));
typedef __bf16 bf16x8 __attribute__((ext_vector_type(8)));
typedef float  f32x4  __attribute__((ext_vector_type(4)));

#define NBATCH 4
#define SEQ    2048
#define DMODEL 512
#define NHEADS 8
#define DHEAD  64
#define DFF    2048
#define MTOT   (NBATCH * SEQ)   // 8192
#define WS_NEED 73416704u
#define QSCALE (0.125f * 1.44269504f)   // 1/sqrt(dk) * log2(e), folded into Q

__device__ __forceinline__ f32x4 mfma16(bf16x8 a, bf16x8 b, f32x4 c) {
    return __builtin_amdgcn_mfma_f32_16x16x32_bf16(a, b, c, 0, 0, 0);
}

// async global->LDS, 16 B/lane. LDS dest = wave-uniform base + lane*16.
__device__ __forceinline__ void lds16(const bf16* g, bf16* l) {
    __builtin_amdgcn_global_load_lds(
        (const __attribute__((address_space(1))) void*)g,
        (__attribute__((address_space(3))) void*)l, 16, 0, 0);
}

__device__ __forceinline__ float scrub(float f) {
    return (fabsf(f) < 1e30f) ? f : 0.f;   // NaN/Inf -> 0 (no-op valid data)
}

// T1 XCD-chunked swizzle for 2D GEMM grids (requires gx*gy % 8 == 0).
__device__ __forceinline__ void xcd_swizzle(int BMv, int BNv, int& mb, int& nb) {
    int gx = gridDim.x, gy = gridDim.y;
    int lin = blockIdx.y * gx + blockIdx.x;
    int q = (gx * gy) >> 3;
    lin = (lin & 7) * q + (lin >> 3);
    int mbi = lin / gy, nbi = lin - mbi * gy;
    mb = mbi * BMv; nb = nbi * BNv;
}

__global__ void sentinel_kernel(bf16* out) {
    out[threadIdx.x] = (bf16)1000.0f;
}

// ---------------------------------------------------------------------------
// prep: x convert + small-param converts + all 6 weight transposes, ONE launch
// ---------------------------------------------------------------------------
__global__ __launch_bounds__(256) void prep_kernel(
        const float* x,
        const float* wq, const float* wk, const float* wv, const float* wo,
        const float* w1, const float* w2,
        const float* bq, const float* bk, const float* bv, const float* bo,
        const float* b1, const float* b2,
        const float* l1a, const float* l1b, const float* l2a, const float* l2b,
        bf16* __restrict__ xcv,
        bf16* __restrict__ wT, bf16* __restrict__ w1T, bf16* __restrict__ w2T,
        bf16* __restrict__ prm) {
    __shared__ bf16 tile[32][33];
    int b = blockIdx.x;
    if (b < 4096) {
        int i = (b * 256 + threadIdx.x) * 4;
        float4 f = *(const float4*)(x + i);
        bf16x4 o = {(bf16)scrub(f.x), (bf16)scrub(f.y),
                    (bf16)scrub(f.z), (bf16)scrub(f.w)};
        *(bf16x4*)(xcv + i) = o;
        return;
    }
    if (b < 4106) {
        int pb = b - 4096;
        const float* srcs[10] = {bq, bk, bv, bo, b1, b2, l1a, l1b, l2a, l2b};
        const int len[10] = {512,512,512,512,2048,512,512,512,512,512};
        const int dst[10] = {0,512,1024,1536,2048,4096,4608,5120,5632,6144};
        const float* s = srcs[pb];
        bf16* d = prm + dst[pb];
        for (int i = threadIdx.x; i < len[pb]; i += 256)
            d[i] = (bf16)scrub(s[i]);
        return;
    }
    const float* in; bf16* out; int K, N, bx, by;
    if (b < 5130) {
        int idx = b - 4106, z = idx >> 8, rem = idx & 255;
        const float* srcs[4] = {wq, wk, wv, wo};
        in = srcs[z]; out = wT + (size_t)z * 262144;
        K = 512; N = 512; bx = rem & 15; by = rem >> 4;
    } else if (b < 6154) {
        int idx = b - 5130;
        in = w1; out = w1T; K = 512; N = 2048; bx = idx & 63; by = idx >> 6;
    } else {
        int idx = b - 6154;
        in = w2; out = w2T; K = 2048; N = 512; bx = idx & 15; by = idx >> 4;
    }
    int tx = threadIdx.x & 31, ty = threadIdx.x >> 5;
    int n0 = bx * 32, k0 = by * 32;
#pragma unroll
    for (int i = 0; i < 4; i++) {
        int kl = ty * 4 + i;
        tile[kl][tx] = (bf16)scrub(in[(size_t)(k0 + kl) * N + n0 + tx]);
    }
    __syncthreads();
#pragma unroll
    for (int i = 0; i < 4; i++) {
        int nl = ty * 4 + i;
        out[(size_t)(n0 + nl) * K + k0 + tx] = tile[tx][nl];
    }
}

// ---------------------------------------------------------------------------
// 256x256 GEMM (FFN1), 8 waves, BK=64, ring-2 LDS, counted vmcnt, T2
// swizzle via pre-swizzled gload_lds source, setprio. r23-verified.
// ---------------------------------------------------------------------------
template <bool RELU>
__global__ __launch_bounds__(512) void gemm256(
        const bf16* __restrict__ A, const bf16* __restrict__ BT,
        const bf16* __restrict__ bias, bf16* __restrict__ Cout,
        int M, int N, int K) {
    __shared__ __align__(16) bf16 Abuf[2][256 * 64];
    __shared__ __align__(16) bf16 Bbuf[2][256 * 64];

    int tid  = threadIdx.x;
    int w    = tid >> 6, lane = tid & 63;
    int quad = lane >> 4, l15 = lane & 15;
    int mb, nb;
    xcd_swizzle(256, 256, mb, nb);
    int wm = (w >> 2) * 128, wn = (w & 3) * 64;

    int srow   = lane >> 3;
    int gchunk = ((lane & 7) ^ srow) << 3;   // inverse-swizzled source col
    int rb0    = w * 32;
    int sw     = l15 & 7;                    // frag-read swizzle (= row&7)

    f32x4 acc[8][4] = {};
    int NT = K >> 6;

#define STAGE256(BUF, KO)                                                    \
    _Pragma("unroll")                                                        \
    for (int a = 0; a < 4; a++) {                                            \
        int rb = rb0 + a * 8;                                                \
        lds16(&A [(size_t)(mb + rb + srow) * K + (KO) + gchunk],             \
              &Abuf[BUF][rb * 64]);                                          \
        lds16(&BT[(size_t)(nb + rb + srow) * K + (KO) + gchunk],             \
              &Bbuf[BUF][rb * 64]);                                          \
    }

    STAGE256(0, 0);

    for (int k = 0; k < NT; k++) {
        if (k + 1 < NT) {
            STAGE256((k + 1) & 1, (k + 1) << 6);
            asm volatile("s_waitcnt vmcnt(8)" ::: "memory");
        } else {
            asm volatile("s_waitcnt vmcnt(0)" ::: "memory");
        }
        __builtin_amdgcn_sched_barrier(0);
        __builtin_amdgcn_s_barrier();
        __builtin_amdgcn_sched_barrier(0);

        const bf16* Ab = &Abuf[k & 1][0];
        const bf16* Bb = &Bbuf[k & 1][0];
        __builtin_amdgcn_s_setprio(1);
#pragma unroll
        for (int ks = 0; ks < 2; ks++) {
            int ch = (((ks << 2) + quad) ^ sw) << 3;
            bf16x8 bfr[4];
#pragma unroll
            for (int j = 0; j < 4; j++)
                bfr[j] = *(const bf16x8*)&Bb[(wn + j * 16 + l15) * 64 + ch];
#pragma unroll
            for (int i = 0; i < 8; i++) {
                bf16x8 af = *(const bf16x8*)&Ab[(wm + i * 16 + l15) * 64 + ch];
#pragma unroll
                for (int j = 0; j < 4; j++)
                    acc[i][j] = mfma16(af, bfr[j], acc[i][j]);
            }
        }
        __builtin_amdgcn_s_setprio(0);
        __builtin_amdgcn_sched_barrier(0);
        __builtin_amdgcn_s_barrier();
        __builtin_amdgcn_sched_barrier(0);
    }
#undef STAGE256

#pragma unroll
    for (int j = 0; j < 4; j++) {
        int n = nb + wn + j * 16 + l15;
        float bv = (float)bias[n];
#pragma unroll
        for (int i = 0; i < 8; i++) {
            int mBase = mb + wm + i * 16 + quad * 4;
#pragma unroll
            for (int r = 0; r < 4; r++) {
                float v = acc[i][j][r] + bv;
                if (RELU) v = v > 0.f ? v : 0.f;
                Cout[(size_t)(mBase + r) * N + n] = (bf16)v;
            }
        }
    }
}

// ---------------------------------------------------------------------------
// Split-K=2 GEMM (BM=64, BN=128, 2-phase stage-ahead), f32 partial output.
// blockIdx.z = K-half. kp0 writes P1 (+bias); kp1 writes P2a (rows<4096)
// / P2b (rows>=4096, rebased). Grid (M/64, N/128, 2) -> 4 blocks/CU.
// ---------------------------------------------------------------------------
__global__ __launch_bounds__(256) void gemm_sk(
        const bf16* __restrict__ A, const bf16* __restrict__ BT,
        const bf16* __restrict__ bias,
        float* __restrict__ P1, float* __restrict__ P2a,
        float* __restrict__ P2b,
        int M, int N, int K) {
    constexpr int BM = 64, BN = 128;
    __shared__ __align__(16) bf16 As0[BM * 32], As1[BM * 32];
    __shared__ __align__(16) bf16 Bs0[BN * 32], Bs1[BN * 32];

    int tid  = threadIdx.x;
    int wid  = tid >> 6, lane = tid & 63;
    int quad = lane >> 4, l15 = lane & 15;
    int mb, nb;
    xcd_swizzle(BM, BN, mb, nb);
    int wm = (wid >> 1) * 32, wn = (wid & 1) * 64;
    int kp = blockIdx.z;
    int kbase = kp * (K >> 1), kend = kbase + (K >> 1);

    f32x4 acc[2][4] = {};

    int cA = wid * 64 + lane;
    int arA = cA >> 2, acA = (cA & 3) * 8;
    int cB0 = wid * 128 + lane, cB1 = cB0 + 64;
    int br0 = cB0 >> 2, bc0 = (cB0 & 3) * 8;
    int br1 = cB1 >> 2, bc1 = (cB1 & 3) * 8;

    lds16(&A [(size_t)(mb + arA) * K + kbase + acA], &As0[wid * 512]);
    lds16(&BT[(size_t)(nb + br0) * K + kbase + bc0], &Bs0[wid * 1024]);
    lds16(&BT[(size_t)(nb + br1) * K + kbase + bc1], &Bs0[wid * 1024 + 512]);
    __syncthreads();

    for (int k0 = kbase; k0 < kend; k0 += 64) {
        lds16(&A [(size_t)(mb + arA) * K + k0 + 32 + acA], &As1[wid * 512]);
        lds16(&BT[(size_t)(nb + br0) * K + k0 + 32 + bc0], &Bs1[wid * 1024]);
        lds16(&BT[(size_t)(nb + br1) * K + k0 + 32 + bc1], &Bs1[wid * 1024 + 512]);
        {
            bf16x8 a0[2], b0[4];
#pragma unroll
            for (int i = 0; i < 2; i++)
                a0[i] = *(const bf16x8*)&As0[(wm + i * 16 + l15) * 32 + quad * 8];
#pragma unroll
            for (int j = 0; j < 4; j++)
                b0[j] = *(const bf16x8*)&Bs0[(wn + j * 16 + l15) * 32 + quad * 8];
#pragma unroll
            for (int i = 0; i < 2; i++)
#pragma unroll
                for (int j = 0; j < 4; j++)
                    acc[i][j] = mfma16(a0[i], b0[j], acc[i][j]);
        }
        __syncthreads();
        if (k0 + 64 < kend) {
            lds16(&A [(size_t)(mb + arA) * K + k0 + 64 + acA], &As0[wid * 512]);
            lds16(&BT[(size_t)(nb + br0) * K + k0 + 64 + bc0], &Bs0[wid * 1024]);
            lds16(&BT[(size_t)(nb + br1) * K + k0 + 64 + bc1], &Bs0[wid * 1024 + 512]);
        }
        {
            bf16x8 a1[2], b1[4];
#pragma unroll
            for (int i = 0; i < 2; i++)
                a1[i] = *(const bf16x8*)&As1[(wm + i * 16 + l15) * 32 + quad * 8];
#pragma unroll
            for (int j = 0; j < 4; j++)
                b1[j] = *(const bf16x8*)&Bs1[(wn + j * 16 + l15) * 32 + quad * 8];
#pragma unroll
            for (int i = 0; i < 2; i++)
#pragma unroll
                for (int j = 0; j < 4; j++)
                    acc[i][j] = mfma16(a1[i], b1[j], acc[i][j]);
        }
        __syncthreads();
    }

#pragma unroll
    for (int j = 0; j < 4; j++) {
        int n = nb + wn + j * 16 + l15;
        float bv = kp ? 0.f : (float)bias[n];
#pragma unroll
        for (int i = 0; i < 2; i++) {
            int mBase = mb + wm + i * 16 + quad * 4;
#pragma unroll
            for (int r = 0; r < 4; r++) {
                int row = mBase + r;
                float v = acc[i][j][r] + bv;
                if (kp == 0) {
                    P1[(size_t)row * N + n] = v;
                } else if (row < 4096) {
                    P2a[(size_t)row * N + n] = v;
                } else {
                    P2b[(size_t)(row - 4096) * N + n] = v;
                }
            }
        }
    }
}

// ---------------------------------------------------------------------------
// Fused QKV GEMM, 2-phase stage-ahead pipeline; region 0 -> Q*(QSCALE),
// 1 -> K, 2 -> V^T via LDS-transposed coalesced epilogue. XCD-swizzled.
// ---------------------------------------------------------------------------
__global__ __launch_bounds__(256) void gemm_qkv(
        const bf16* __restrict__ A, const bf16* __restrict__ BT,
        const bf16* __restrict__ bias,
        bf16* __restrict__ Cq, bf16* __restrict__ Ck, bf16* __restrict__ Cv,
        int M, int N, int K) {
    constexpr int BM = 128, BN = 128;
    __shared__ __align__(16) bf16 As0[BM * 32], As1[BM * 32];
    __shared__ __align__(16) bf16 Bs0[BN * 32], Bs1[BN * 32];
    __shared__ __align__(16) bf16 Ts[128 * 136];

    int tid  = threadIdx.x;
    int wid  = tid >> 6, lane = tid & 63;
    int quad = lane >> 4, l15 = lane & 15;
    int mb, nb;
    xcd_swizzle(BM, BN, mb, nb);
    int wm = (wid >> 1) * 64, wn = (wid & 1) * 64;

    f32x4 acc[4][4] = {};

    int c0 = wid * 128 + lane, c1 = c0 + 64;
    int ar0 = c0 >> 2, ac0 = (c0 & 3) * 8;
    int ar1 = c1 >> 2, ac1 = (c1 & 3) * 8;
    int o0 = wid * 1024, o1 = wid * 1024 + 512;

    lds16(&A [(size_t)(mb + ar0) * K + ac0], &As0[o0]);
    lds16(&A [(size_t)(mb + ar1) * K + ac1], &As0[o1]);
    lds16(&BT[(size_t)(nb + ar0) * K + ac0], &Bs0[o0]);
    lds16(&BT[(size_t)(nb + ar1) * K + ac1], &Bs0[o1]);
    __syncthreads();

    for (int k0 = 0; k0 < K; k0 += 64) {
        lds16(&A [(size_t)(mb + ar0) * K + k0 + 32 + ac0], &As1[o0]);
        lds16(&A [(size_t)(mb + ar1) * K + k0 + 32 + ac1], &As1[o1]);
        lds16(&BT[(size_t)(nb + ar0) * K + k0 + 32 + ac0], &Bs1[o0]);
        lds16(&BT[(size_t)(nb + ar1) * K + k0 + 32 + ac1], &Bs1[o1]);
        {
            bf16x8 af[4], bfr[4];
#pragma unroll
            for (int i = 0; i < 4; i++)
                af[i] = *(const bf16x8*)&As0[(wm + i * 16 + l15) * 32 + quad * 8];
#pragma unroll
            for (int j = 0; j < 4; j++)
                bfr[j] = *(const bf16x8*)&Bs0[(wn + j * 16 + l15) * 32 + quad * 8];
#pragma unroll
            for (int i = 0; i < 4; i++)
#pragma unroll
                for (int j = 0; j < 4; j++)
                    acc[i][j] = mfma16(af[i], bfr[j], acc[i][j]);
        }
        __syncthreads();
        if (k0 + 64 < K) {
            lds16(&A [(size_t)(mb + ar0) * K + k0 + 64 + ac0], &As0[o0]);
            lds16(&A [(size_t)(mb + ar1) * K + k0 + 64 + ac1], &As0[o1]);
            lds16(&BT[(size_t)(nb + ar0) * K + k0 + 64 + ac0], &Bs0[o0]);
            lds16(&BT[(size_t)(nb + ar1) * K + k0 + 64 + ac1], &Bs0[o1]);
        }
        {
            bf16x8 af[4], bfr[4];
#pragma unroll
            for (int i = 0; i < 4; i++)
                af[i] = *(const bf16x8*)&As1[(wm + i * 16 + l15) * 32 + quad * 8];
#pragma unroll
            for (int j = 0; j < 4; j++)
                bfr[j] = *(const bf16x8*)&Bs1[(wn + j * 16 + l15) * 32 + quad * 8];
#pragma unroll
            for (int i = 0; i < 4; i++)
#pragma unroll
                for (int j = 0; j < 4; j++)
                    acc[i][j] = mfma16(af[i], bfr[j], acc[i][j]);
        }
        __syncthreads();
    }

    int reg = nb >> 9;   // 0=Q, 1=K, 2=V
    if (reg < 2) {
        bf16* C = reg ? Ck : Cq;
        float scl = reg ? 1.0f : QSCALE;
#pragma unroll
        for (int j = 0; j < 4; j++) {
            int n = nb + wn + j * 16 + l15;
            float bv = (float)bias[n];
            int nn = n & 511;
            int h = nn >> 6, dk = nn & 63;
#pragma unroll
            for (int i = 0; i < 4; i++) {
                int mBase = mb + wm + i * 16 + quad * 4;
#pragma unroll
                for (int r = 0; r < 4; r++) {
                    float v = (acc[i][j][r] + bv) * scl;
                    int m = mBase + r;
                    int b = m >> 11, s = m & (SEQ - 1);
                    C[((size_t)(b * NHEADS + h) * SEQ + s) * DHEAD + dk] = (bf16)v;
                }
            }
        }
    } else {
#pragma unroll
        for (int j = 0; j < 4; j++) {
            int nl = wn + j * 16 + l15;
            float bv = (float)bias[nb + nl];
#pragma unroll
            for (int i = 0; i < 4; i++) {
                int ml = wm + i * 16 + quad * 4;
                bf16x4 pk;
#pragma unroll
                for (int r = 0; r < 4; r++) pk[r] = (bf16)(acc[i][j][r] + bv);
                *(bf16x4*)&Ts[nl * 136 + ml] = pk;
            }
        }
        __syncthreads();
        int nl = tid >> 1, half = tid & 1;
        int nn = (nb + nl) & 511;
        int h = nn >> 6, dk = nn & 63;
        int bb = mb >> 11, s0 = mb & (SEQ - 1);
        bf16* dst = &Cv[((size_t)(bb * NHEADS + h) * DHEAD + dk) * SEQ + s0 + half * 64];
        const bf16* srcl = &Ts[nl * 136 + half * 64];
#pragma unroll
        for (int v = 0; v < 8; v++)
            *(uint4*)(dst + v * 8) = *(const uint4*)(srcl + v * 8);
    }
}

// ---------------------------------------------------------------------------
// Flash attention: grid (16, 32), block 256 = 4 waves, direct bf16 out.
// r22 structure: swizzled LDS via inverse-swizzled gload_lds source;
// conflict-free frag reads; l-row via MFMA ones-trick; setprio; XCD swizzle.
// ---------------------------------------------------------------------------
__global__ __launch_bounds__(256) void attn_kernel(
        const bf16* __restrict__ Q, const bf16* __restrict__ K,
        const bf16* __restrict__ VT, bf16* __restrict__ Out) {
    __shared__ __align__(16) bf16 Ks[2][64 * 64];
    __shared__ __align__(16) bf16 Vs[2][64 * 64];
    __shared__ __align__(16) bf16 Pb[4][16 * 64];
    int tid  = threadIdx.x;
    int wid  = tid >> 6, lane = tid & 63;
    int quad = lane >> 4, l15 = lane & 15;

    int lin = blockIdx.y * 16 + blockIdx.x;        // grid is (16, 32)
    lin = (lin & 7) * 64 + (lin >> 3);             // bijective (512 = 8*64)
    int bh = lin >> 4;
    int qb = (lin & 15) * 128 + wid * 32;

    const bf16* Qh = Q  + (size_t)bh * SEQ * DHEAD;
    const bf16* Kh = K  + (size_t)bh * SEQ * DHEAD;
    const bf16* Vh = VT + (size_t)bh * DHEAD * SEQ;

    bf16x8 bQ0[2], bQ1[2];
#pragma unroll
    for (int c = 0; c < 2; c++) {
        const bf16* qp = &Qh[(qb + c * 16 + l15) * DHEAD + quad * 8];
        bQ0[c] = *(const bf16x8*)qp;
        bQ1[c] = *(const bf16x8*)(qp + 32);
    }

    bf16x8 vONE;
#pragma unroll
    for (int i = 0; i < 8; i++) vONE[i] = (bf16)1.0f;

    int srow = lane >> 3;
    int scol = ((lane & 7) ^ srow) << 3;   // global col offset (elems)
    int ldsb = wid * 1024;                 // wave's LDS base (elems)
    int krA = wid * 16 + srow, krB = krA + 8;

    int r7q = l15 & 7;
    int e0 = ((quad ^ r7q) << 3);
    int e1 = e0 ^ 32;

    f32x4 lacc[2] = {};
    f32x4 Oacc[2][4] = {};

    lds16(&Kh[(size_t)krA * DHEAD + scol], &Ks[0][ldsb]);
    lds16(&Kh[(size_t)krB * DHEAD + scol], &Ks[0][ldsb + 512]);
    lds16(&Vh[(size_t)krA * SEQ + scol],   &Vs[0][ldsb]);
    lds16(&Vh[(size_t)krB * SEQ + scol],   &Vs[0][ldsb + 512]);
    __syncthreads();

#define ATTN_STEP(CUR, NXT, KB, PF)                                          \
    {                                                                        \
        if (PF) {                                                            \
            lds16(&Kh[(size_t)((KB) + krA) * DHEAD + scol], &Ks[NXT][ldsb]); \
            lds16(&Kh[(size_t)((KB) + krB) * DHEAD + scol],                  \
                  &Ks[NXT][ldsb + 512]);                                     \
            lds16(&Vh[(size_t)krA * SEQ + (KB) + scol], &Vs[NXT][ldsb]);     \
            lds16(&Vh[(size_t)krB * SEQ + (KB) + scol],                      \
                  &Vs[NXT][ldsb + 512]);                                     \
        }                                                                    \
        bf16x8 aK0[4], aK1[4], bV0[4], bV1[4];                               \
        _Pragma("unroll")                                                    \
        for (int t = 0; t < 4; t++) {                                        \
            const bf16* kp = &Ks[CUR][(t * 16 + l15) * 64];                  \
            aK0[t] = *(const bf16x8*)(kp + e0);                              \
            aK1[t] = *(const bf16x8*)(kp + e1);                              \
            const bf16* vp = &Vs[CUR][(t * 16 + l15) * 64];                  \
            bV0[t] = *(const bf16x8*)(vp + e0);                              \
            bV1[t] = *(const bf16x8*)(vp + e1);                              \
        }                                                                    \
        _Pragma("unroll")                                                    \
        for (int c = 0; c < 2; c++) {                                        \
            __builtin_amdgcn_s_setprio(1);                                   \
            f32x4 st[4];                                                     \
            _Pragma("unroll")                                                \
            for (int t = 0; t < 4; t++) {                                    \
                f32x4 zv = {0.f, 0.f, 0.f, 0.f};                             \
                st[t] = mfma16(aK1[t], bQ1[c], mfma16(aK0[t], bQ0[c], zv));  \
            }                                                                \
            bf16* myP = Pb[wid];                                             \
            _Pragma("unroll")                                                \
            for (int t = 0; t < 4; t++) {                                    \
                bf16x4 pk;                                                   \
                _Pragma("unroll")                                            \
                for (int r = 0; r < 4; r++)                                  \
                    pk[r] = (bf16)__builtin_amdgcn_exp2f(                    \
                                fminf(st[t][r], 60.f));                      \
                int pch = ((2 * t + (quad >> 1)) ^ r7q) << 3;                \
                *(bf16x4*)&myP[l15 * 64 + pch + ((quad & 1) << 2)] = pk;     \
            }                                                                \
            bf16x8 aP0 = *(const bf16x8*)&myP[l15 * 64 + e0];                \
            bf16x8 aP1 = *(const bf16x8*)&myP[l15 * 64 + e1];                \
            _Pragma("unroll")                                                \
            for (int nt = 0; nt < 4; nt++)                                   \
                Oacc[c][nt] = mfma16(aP1, bV1[nt],                           \
                                     mfma16(aP0, bV0[nt], Oacc[c][nt]));     \
            lacc[c] = mfma16(aP1, vONE, mfma16(aP0, vONE, lacc[c]));         \
            __builtin_amdgcn_s_setprio(0);                                   \
        }                                                                    \
        __syncthreads();                                                     \
    }

    for (int it2 = 0; it2 < SEQ / 128; it2++) {
        ATTN_STEP(0, 1, (2 * it2 + 1) * 64, true);
        ATTN_STEP(1, 0, (2 * it2 + 2) * 64, (it2 + 1 < SEQ / 128));
    }
#undef ATTN_STEP

    int b = bh >> 3, hd = bh & 7;
#pragma unroll
    for (int c = 0; c < 2; c++) {
        float linv[4];
#pragma unroll
        for (int r = 0; r < 4; r++)
            linv[r] = 1.f / lacc[c][r];
#pragma unroll
        for (int nt = 0; nt < 4; nt++)
#pragma unroll
            for (int r = 0; r < 4; r++) {
                int s = qb + c * 16 + quad * 4 + r;
                Out[((size_t)(b * SEQ + s)) * DMODEL + hd * 64 + nt * 16 + l15]
                    = (bf16)(Oacc[c][nt][r] * linv[r]);
            }
    }
}

// ---------------------------------------------------------------------------
// Residual + split-K-combine + LayerNorm: v = X + P1 + P2 (f32), then LN
// (unbiased std ddof=1, eps added to std). P2 = P2a rows<4096 else P2b
// (rebased). NOTE: Out may alias P1 (in-place, per-row exclusive) -- no
// __restrict__ on P1/Out.
// ---------------------------------------------------------------------------
__global__ __launch_bounds__(256) void lnsk_kernel(
        const bf16* __restrict__ X, const float* P1,
        const float* __restrict__ P2a, const float* __restrict__ P2b,
        const bf16* __restrict__ Al, const bf16* __restrict__ Bl,
        void* Out, int final_out) {
    int wid = threadIdx.x >> 6, lane = threadIdx.x & 63;
    int row = blockIdx.x * 4 + wid;
    const bf16*  xr = X  + (size_t)row * DMODEL;
    const float* p1 = P1 + (size_t)row * DMODEL;
    const float* p2 = (row < 4096) ? P2a + (size_t)row * DMODEL
                                   : P2b + (size_t)(row - 4096) * DMODEL;
    bf16x8 xv = *(const bf16x8*)&xr[lane * 8];
    float4 a0 = *(const float4*)&p1[lane * 8];
    float4 a1 = *(const float4*)&p1[lane * 8 + 4];
    float4 c0 = *(const float4*)&p2[lane * 8];
    float4 c1 = *(const float4*)&p2[lane * 8 + 4];
    float v[8] = {
        (float)xv[0] + a0.x + c0.x, (float)xv[1] + a0.y + c0.y,
        (float)xv[2] + a0.z + c0.z, (float)xv[3] + a0.w + c0.w,
        (float)xv[4] + a1.x + c1.x, (float)xv[5] + a1.y + c1.y,
        (float)xv[6] + a1.z + c1.z, (float)xv[7] + a1.w + c1.w};
    float sum = 0.f, sq = 0.f;
#pragma unroll
    for (int i = 0; i < 8; i++) { sum += v[i]; sq += v[i] * v[i]; }
#pragma unroll
    for (int m = 1; m < 64; m <<= 1) {
        sum += __shfl_xor(sum, m);
        sq  += __shfl_xor(sq,  m);
    }
    float mean = sum * (1.f / DMODEL);
    float var  = (sq - DMODEL * mean * mean) * (1.f / (DMODEL - 1));
    var = var > 0.f ? var : 0.f;
    float inv = 1.f / (sqrtf(var) + 1e-6f);
#pragma unroll
    for (int i = 0; i < 8; i++) {
        int c = lane * 8 + i;
        float yv = (float)Al[c] * (v[i] - mean) * inv + (float)Bl[c];
        yv = fminf(fmaxf(yv, -1e4f), 1e4f);
        size_t idx = (size_t)row * DMODEL + c;
        if (final_out) ((float*)Out)[idx] = yv;
        else           ((bf16*)Out)[idx]  = (bf16)yv;
    }
}

// ---------------------------------------------------------------------------
extern "C" void kernel_launch(void* const* d_in, const int* in_sizes, int n_in,
                              void* d_out, int out_size, void* d_ws, size_t ws_size,
                              hipStream_t stream) {
    if (ws_size < WS_NEED) {
        sentinel_kernel<<<1, 64, 0, stream>>>((bf16*)d_out);
        return;
    }

    const float* x  = (const float*)d_in[0];
    const float* wq = (const float*)d_in[1],  *bq = (const float*)d_in[2];
    const float* wk = (const float*)d_in[3],  *bk = (const float*)d_in[4];
    const float* wv = (const float*)d_in[5],  *bv = (const float*)d_in[6];
    const float* wo = (const float*)d_in[7],  *bo = (const float*)d_in[8];
    const float* w1 = (const float*)d_in[9],  *b1 = (const float*)d_in[10];
    const float* w2 = (const float*)d_in[11], *b2 = (const float*)d_in[12];
    const float* ln1a = (const float*)d_in[13], *ln1b = (const float*)d_in[14];
    const float* ln2a = (const float*)d_in[15], *ln2b = (const float*)d_in[16];

    char* ws = (char*)d_ws;
    bf16* wT   = (bf16*)(ws + 0);
    bf16* woT  = (bf16*)(ws + 1572864);
    bf16* w1T  = (bf16*)(ws + 2097152);
    bf16* w2T  = (bf16*)(ws + 4194304);
    bf16* xcv  = (bf16*)(ws + 6291456);
    bf16* prm  = (bf16*)(ws + 14680064);
    bf16* regA = (bf16*)(ws + 14696448);
    bf16* regB = (bf16*)(ws + 23085056);
    bf16* regC = (bf16*)(ws + 31473664);
    bf16* ff1  = (bf16*)(ws + 39862272);
    bf16* aout = (bf16*)d_out;   // attn output scratch (bf16)

    // oproj split-K partials live in the (idle until ffn1) ff1 region
    float* oP1 = (float*)(ws + 39862272);              // 16 MB
    float* oP2 = oP1 + 4194304;                        // 16 MB (4M floats)
    // ffn2 split-K partials
    float* fP1  = (float*)d_out;                       // 16 MB (after aout consumed)
    float* fP2a = (float*)regA;                        // rows 0..4095   (8 MB)
    float* fP2b = (float*)regC;                        // rows 4096..8191 (8 MB)

    bf16 *pbq = prm, *pbo = prm + 1536;
    bf16 *pb1 = prm + 2048, *pb2 = prm + 4096;
    bf16 *pl1a = prm + 4608, *pl1b = prm + 5120;
    bf16 *pl2a = prm + 5632, *pl2b = prm + 6144;

    prep_kernel<<<7178, 256, 0, stream>>>(x, wq, wk, wv, wo, w1, w2,
                                          bq, bk, bv, bo, b1, b2,
                                          ln1a, ln1b, ln2a, ln2b,
                                          xcv, wT, w1T, w2T, prm);

    // fused QKV projection (Q pre-scaled by QSCALE; V^T coalesced epilogue)
    gemm_qkv<<<dim3(64, 12), 256, 0, stream>>>(xcv, wT, pbq,
                                               regA, regB, regC,
                                               MTOT, 3 * DMODEL, DMODEL);

    // attention -> d_out (scratch), direct bf16
    attn_kernel<<<dim3(SEQ / 128, NBATCH * NHEADS), 256, 0, stream>>>(
        regA, regB, regC, aout);

    // O-proj split-K=2: aout -> f32 partials in ff1 region (4 blocks/CU)
    gemm_sk<<<dim3(128, 4, 2), 256, 0, stream>>>(
        aout, woT, pbo, oP1, oP2, oP2 + (size_t)4096 * DMODEL,
        MTOT, DMODEL, DMODEL);

    // LN1: xcv + (oP1 + oP2) -> y (regB, bf16)
    lnsk_kernel<<<MTOT / 4, 256, 0, stream>>>(
        xcv, oP1, oP2, oP2 + (size_t)4096 * DMODEL, pl1a, pl1b, regB, 0);

    // FFN1: y -> ff1 (ReLU), 256^2 counted-vmcnt kernel
    gemm256<true><<<dim3(32, 8), 512, 0, stream>>>(regB, w1T, pb1, ff1,
                                                   MTOT, DFF, DMODEL);

    // FFN2 split-K=2: ff1 -> f32 partials (d_out + regA/regC, 4 blocks/CU)
    gemm_sk<<<dim3(128, 4, 2), 256, 0, stream>>>(
        ff1, w2T, pb2, fP1, fP2a, fP2b, MTOT, DMODEL, DFF);

    // LN2: y + (fP1 + fP2) -> out (fp32, in-place over fP1; per-row safe)
    lnsk_kernel<<<MTOT / 4, 256, 0, stream>>>(
        regB, fP1, fP2a, fP2b, pl2a, pl2b, d_out, 1);
}

// Round 12
// 281.245 us; speedup vs baseline: 1.0217x; 1.0217x over previous
//
#include <hip/hip_runtime.h>
#include <hip/hip_bf16.h>

// ---------------------------------------------------------------------------
// EncoderBlock on MI355X (gfx950). Round 25.
// r24 post-mortem: split-K=2 for oproj/ffn2 REGRESSED (287.4 vs 278.9):
// +96MB f32 partial traffic cost ~8.5us and the drain-overlap gain never
// appeared -- with r18's attn split-K null this proves these stalls are
// per-block serial (stage->drain->compute), not curable by blocks/CU.
// Full revert to r23 config. r25 lever (T4 applied to attn): the attn
// step ended in __syncthreads whose vmcnt(0) semantics DRAIN the 4 just-
// issued next-tile prefetch loads at every one of 32 steps (m97-style
// barrier drain). Replace with counted vmcnt(4) + raw s_barrier: each
// wave waits only for its OWN current tile's 4 loads (issued last step);
// the next tile's 4 stay in flight across compute AND the trailing
// barrier. WAR on the re-staged buffer is protected by the trailing raw
// barrier (frag reads consumed before any wave reaches it); P is wave-
// private; sched_barrier(0) fences per rule #18. Last step: vmcnt(0).
//
// ws layout (bytes), WS_NEED = 73416704, sentinel-guarded:
//   [0,        2097152)  wq|wk|wv|wo T (bf16)
//   [2097152,  4194304)  w1T
//   [4194304,  6291456)  w2T
//   [6291456, 14680064)  xcv: x as bf16 (8 MB)
//   [14680064,14696448)  small params (bf16)
//   A [14696448,23085056) qbuf -> t -> ff2      (8 MB)
//   B [23085056,31473664) kbuf -> y             (8 MB)
//   C [31473664,39862272) vT                    (8 MB)
//   F [39862272,73416704) ff1 (32 MB)
//   d_out                attn output scratch (bf16) -> final output (fp32)
// ---------------------------------------------------------------------------

typedef __bf16 bf16;
typedef __bf16 bf16x4 __attribute__((ext_vector_type(4)));
typedef __bf16 bf16x8 __attribute__((ext_vector_type(8)));
typedef float  f32x4  __attribute__((ext_vector_type(4)));

#define NBATCH 4
#define SEQ    2048
#define DMODEL 512
#define NHEADS 8
#define DHEAD  64
#define DFF    2048
#define MTOT   (NBATCH * SEQ)   // 8192
#define WS_NEED 73416704u
#define QSCALE (0.125f * 1.44269504f)   // 1/sqrt(dk) * log2(e), folded into Q

__device__ __forceinline__ f32x4 mfma16(bf16x8 a, bf16x8 b, f32x4 c) {
    return __builtin_amdgcn_mfma_f32_16x16x32_bf16(a, b, c, 0, 0, 0);
}

// async global->LDS, 16 B/lane. LDS dest = wave-uniform base + lane*16.
__device__ __forceinline__ void lds16(const bf16* g, bf16* l) {
    __builtin_amdgcn_global_load_lds(
        (const __attribute__((address_space(1))) void*)g,
        (__attribute__((address_space(3))) void*)l, 16, 0, 0);
}

__device__ __forceinline__ float scrub(float f) {
    return (fabsf(f) < 1e30f) ? f : 0.f;   // NaN/Inf -> 0 (no-op valid data)
}

// T1 XCD-chunked swizzle for 2D GEMM grids (requires gx*gy % 8 == 0).
__device__ __forceinline__ void xcd_swizzle(int BMv, int BNv, int& mb, int& nb) {
    int gx = gridDim.x, gy = gridDim.y;
    int lin = blockIdx.y * gx + blockIdx.x;
    int q = (gx * gy) >> 3;
    lin = (lin & 7) * q + (lin >> 3);
    int mbi = lin / gy, nbi = lin - mbi * gy;
    mb = mbi * BMv; nb = nbi * BNv;
}

__global__ void sentinel_kernel(bf16* out) {
    out[threadIdx.x] = (bf16)1000.0f;
}

// ---------------------------------------------------------------------------
// prep: x convert + small-param converts + all 6 weight transposes, ONE launch
// ---------------------------------------------------------------------------
__global__ __launch_bounds__(256) void prep_kernel(
        const float* x,
        const float* wq, const float* wk, const float* wv, const float* wo,
        const float* w1, const float* w2,
        const float* bq, const float* bk, const float* bv, const float* bo,
        const float* b1, const float* b2,
        const float* l1a, const float* l1b, const float* l2a, const float* l2b,
        bf16* __restrict__ xcv,
        bf16* __restrict__ wT, bf16* __restrict__ w1T, bf16* __restrict__ w2T,
        bf16* __restrict__ prm) {
    __shared__ bf16 tile[32][33];
    int b = blockIdx.x;
    if (b < 4096) {
        int i = (b * 256 + threadIdx.x) * 4;
        float4 f = *(const float4*)(x + i);
        bf16x4 o = {(bf16)scrub(f.x), (bf16)scrub(f.y),
                    (bf16)scrub(f.z), (bf16)scrub(f.w)};
        *(bf16x4*)(xcv + i) = o;
        return;
    }
    if (b < 4106) {
        int pb = b - 4096;
        const float* srcs[10] = {bq, bk, bv, bo, b1, b2, l1a, l1b, l2a, l2b};
        const int len[10] = {512,512,512,512,2048,512,512,512,512,512};
        const int dst[10] = {0,512,1024,1536,2048,4096,4608,5120,5632,6144};
        const float* s = srcs[pb];
        bf16* d = prm + dst[pb];
        for (int i = threadIdx.x; i < len[pb]; i += 256)
            d[i] = (bf16)scrub(s[i]);
        return;
    }
    const float* in; bf16* out; int K, N, bx, by;
    if (b < 5130) {
        int idx = b - 4106, z = idx >> 8, rem = idx & 255;
        const float* srcs[4] = {wq, wk, wv, wo};
        in = srcs[z]; out = wT + (size_t)z * 262144;
        K = 512; N = 512; bx = rem & 15; by = rem >> 4;
    } else if (b < 6154) {
        int idx = b - 5130;
        in = w1; out = w1T; K = 512; N = 2048; bx = idx & 63; by = idx >> 6;
    } else {
        int idx = b - 6154;
        in = w2; out = w2T; K = 2048; N = 512; bx = idx & 15; by = idx >> 4;
    }
    int tx = threadIdx.x & 31, ty = threadIdx.x >> 5;
    int n0 = bx * 32, k0 = by * 32;
#pragma unroll
    for (int i = 0; i < 4; i++) {
        int kl = ty * 4 + i;
        tile[kl][tx] = (bf16)scrub(in[(size_t)(k0 + kl) * N + n0 + tx]);
    }
    __syncthreads();
#pragma unroll
    for (int i = 0; i < 4; i++) {
        int nl = ty * 4 + i;
        out[(size_t)(n0 + nl) * K + k0 + tx] = tile[tx][nl];
    }
}

// ---------------------------------------------------------------------------
// 256x256 GEMM (FFN1), 8 waves, BK=64, ring-2 LDS, counted vmcnt, T2
// swizzle via pre-swizzled gload_lds source, setprio. r23-verified.
// ---------------------------------------------------------------------------
template <bool RELU>
__global__ __launch_bounds__(512) void gemm256(
        const bf16* __restrict__ A, const bf16* __restrict__ BT,
        const bf16* __restrict__ bias, bf16* __restrict__ Cout,
        int M, int N, int K) {
    __shared__ __align__(16) bf16 Abuf[2][256 * 64];
    __shared__ __align__(16) bf16 Bbuf[2][256 * 64];

    int tid  = threadIdx.x;
    int w    = tid >> 6, lane = tid & 63;
    int quad = lane >> 4, l15 = lane & 15;
    int mb, nb;
    xcd_swizzle(256, 256, mb, nb);
    int wm = (w >> 2) * 128, wn = (w & 3) * 64;

    int srow   = lane >> 3;
    int gchunk = ((lane & 7) ^ srow) << 3;   // inverse-swizzled source col
    int rb0    = w * 32;
    int sw     = l15 & 7;                    // frag-read swizzle (= row&7)

    f32x4 acc[8][4] = {};
    int NT = K >> 6;

#define STAGE256(BUF, KO)                                                    \
    _Pragma("unroll")                                                        \
    for (int a = 0; a < 4; a++) {                                            \
        int rb = rb0 + a * 8;                                                \
        lds16(&A [(size_t)(mb + rb + srow) * K + (KO) + gchunk],             \
              &Abuf[BUF][rb * 64]);                                          \
        lds16(&BT[(size_t)(nb + rb + srow) * K + (KO) + gchunk],             \
              &Bbuf[BUF][rb * 64]);                                          \
    }

    STAGE256(0, 0);

    for (int k = 0; k < NT; k++) {
        if (k + 1 < NT) {
            STAGE256((k + 1) & 1, (k + 1) << 6);
            asm volatile("s_waitcnt vmcnt(8)" ::: "memory");
        } else {
            asm volatile("s_waitcnt vmcnt(0)" ::: "memory");
        }
        __builtin_amdgcn_sched_barrier(0);
        __builtin_amdgcn_s_barrier();
        __builtin_amdgcn_sched_barrier(0);

        const bf16* Ab = &Abuf[k & 1][0];
        const bf16* Bb = &Bbuf[k & 1][0];
        __builtin_amdgcn_s_setprio(1);
#pragma unroll
        for (int ks = 0; ks < 2; ks++) {
            int ch = (((ks << 2) + quad) ^ sw) << 3;
            bf16x8 bfr[4];
#pragma unroll
            for (int j = 0; j < 4; j++)
                bfr[j] = *(const bf16x8*)&Bb[(wn + j * 16 + l15) * 64 + ch];
#pragma unroll
            for (int i = 0; i < 8; i++) {
                bf16x8 af = *(const bf16x8*)&Ab[(wm + i * 16 + l15) * 64 + ch];
#pragma unroll
                for (int j = 0; j < 4; j++)
                    acc[i][j] = mfma16(af, bfr[j], acc[i][j]);
            }
        }
        __builtin_amdgcn_s_setprio(0);
        __builtin_amdgcn_sched_barrier(0);
        __builtin_amdgcn_s_barrier();
        __builtin_amdgcn_sched_barrier(0);
    }
#undef STAGE256

#pragma unroll
    for (int j = 0; j < 4; j++) {
        int n = nb + wn + j * 16 + l15;
        float bv = (float)bias[n];
#pragma unroll
        for (int i = 0; i < 8; i++) {
            int mBase = mb + wm + i * 16 + quad * 4;
#pragma unroll
            for (int r = 0; r < 4; r++) {
                float v = acc[i][j][r] + bv;
                if (RELU) v = v > 0.f ? v : 0.f;
                Cout[(size_t)(mBase + r) * N + n] = (bf16)v;
            }
        }
    }
}

// ---------------------------------------------------------------------------
// BM=64, BN=128 GEMM, 2-phase stage-ahead pipeline. For O-proj / FFN2.
// ---------------------------------------------------------------------------
template <bool RELU>
__global__ __launch_bounds__(256) void gemm_bt64(
        const bf16* __restrict__ A, const bf16* __restrict__ BT,
        const bf16* __restrict__ bias, bf16* __restrict__ Cout,
        int M, int N, int K) {
    constexpr int BM = 64, BN = 128;
    __shared__ __align__(16) bf16 As0[BM * 32], As1[BM * 32];
    __shared__ __align__(16) bf16 Bs0[BN * 32], Bs1[BN * 32];

    int tid  = threadIdx.x;
    int wid  = tid >> 6, lane = tid & 63;
    int quad = lane >> 4, l15 = lane & 15;
    int mb, nb;
    xcd_swizzle(BM, BN, mb, nb);
    int wm = (wid >> 1) * 32, wn = (wid & 1) * 64;

    f32x4 acc[2][4] = {};

    int cA = wid * 64 + lane;
    int arA = cA >> 2, acA = (cA & 3) * 8;
    int cB0 = wid * 128 + lane, cB1 = cB0 + 64;
    int br0 = cB0 >> 2, bc0 = (cB0 & 3) * 8;
    int br1 = cB1 >> 2, bc1 = (cB1 & 3) * 8;

    lds16(&A [(size_t)(mb + arA) * K + acA], &As0[wid * 512]);
    lds16(&BT[(size_t)(nb + br0) * K + bc0], &Bs0[wid * 1024]);
    lds16(&BT[(size_t)(nb + br1) * K + bc1], &Bs0[wid * 1024 + 512]);
    __syncthreads();

    for (int k0 = 0; k0 < K; k0 += 64) {
        lds16(&A [(size_t)(mb + arA) * K + k0 + 32 + acA], &As1[wid * 512]);
        lds16(&BT[(size_t)(nb + br0) * K + k0 + 32 + bc0], &Bs1[wid * 1024]);
        lds16(&BT[(size_t)(nb + br1) * K + k0 + 32 + bc1], &Bs1[wid * 1024 + 512]);
        {
            bf16x8 a0[2], b0[4];
#pragma unroll
            for (int i = 0; i < 2; i++)
                a0[i] = *(const bf16x8*)&As0[(wm + i * 16 + l15) * 32 + quad * 8];
#pragma unroll
            for (int j = 0; j < 4; j++)
                b0[j] = *(const bf16x8*)&Bs0[(wn + j * 16 + l15) * 32 + quad * 8];
#pragma unroll
            for (int i = 0; i < 2; i++)
#pragma unroll
                for (int j = 0; j < 4; j++)
                    acc[i][j] = mfma16(a0[i], b0[j], acc[i][j]);
        }
        __syncthreads();
        if (k0 + 64 < K) {
            lds16(&A [(size_t)(mb + arA) * K + k0 + 64 + acA], &As0[wid * 512]);
            lds16(&BT[(size_t)(nb + br0) * K + k0 + 64 + bc0], &Bs0[wid * 1024]);
            lds16(&BT[(size_t)(nb + br1) * K + k0 + 64 + bc1], &Bs0[wid * 1024 + 512]);
        }
        {
            bf16x8 a1[2], b1[4];
#pragma unroll
            for (int i = 0; i < 2; i++)
                a1[i] = *(const bf16x8*)&As1[(wm + i * 16 + l15) * 32 + quad * 8];
#pragma unroll
            for (int j = 0; j < 4; j++)
                b1[j] = *(const bf16x8*)&Bs1[(wn + j * 16 + l15) * 32 + quad * 8];
#pragma unroll
            for (int i = 0; i < 2; i++)
#pragma unroll
                for (int j = 0; j < 4; j++)
                    acc[i][j] = mfma16(a1[i], b1[j], acc[i][j]);
        }
        __syncthreads();
    }

#pragma unroll
    for (int j = 0; j < 4; j++) {
        int n = nb + wn + j * 16 + l15;
        float bv = (float)bias[n];
#pragma unroll
        for (int i = 0; i < 2; i++) {
            int mBase = mb + wm + i * 16 + quad * 4;
#pragma unroll
            for (int r = 0; r < 4; r++) {
                float v = acc[i][j][r] + bv;
                if (RELU) v = v > 0.f ? v : 0.f;
                Cout[(size_t)(mBase + r) * N + n] = (bf16)v;
            }
        }
    }
}

// ---------------------------------------------------------------------------
// Fused QKV GEMM, 2-phase stage-ahead pipeline; region 0 -> Q*(QSCALE),
// 1 -> K, 2 -> V^T via LDS-transposed coalesced epilogue. XCD-swizzled.
// ---------------------------------------------------------------------------
__global__ __launch_bounds__(256) void gemm_qkv(
        const bf16* __restrict__ A, const bf16* __restrict__ BT,
        const bf16* __restrict__ bias,
        bf16* __restrict__ Cq, bf16* __restrict__ Ck, bf16* __restrict__ Cv,
        int M, int N, int K) {
    constexpr int BM = 128, BN = 128;
    __shared__ __align__(16) bf16 As0[BM * 32], As1[BM * 32];
    __shared__ __align__(16) bf16 Bs0[BN * 32], Bs1[BN * 32];
    __shared__ __align__(16) bf16 Ts[128 * 136];

    int tid  = threadIdx.x;
    int wid  = tid >> 6, lane = tid & 63;
    int quad = lane >> 4, l15 = lane & 15;
    int mb, nb;
    xcd_swizzle(BM, BN, mb, nb);
    int wm = (wid >> 1) * 64, wn = (wid & 1) * 64;

    f32x4 acc[4][4] = {};

    int c0 = wid * 128 + lane, c1 = c0 + 64;
    int ar0 = c0 >> 2, ac0 = (c0 & 3) * 8;
    int ar1 = c1 >> 2, ac1 = (c1 & 3) * 8;
    int o0 = wid * 1024, o1 = wid * 1024 + 512;

    lds16(&A [(size_t)(mb + ar0) * K + ac0], &As0[o0]);
    lds16(&A [(size_t)(mb + ar1) * K + ac1], &As0[o1]);
    lds16(&BT[(size_t)(nb + ar0) * K + ac0], &Bs0[o0]);
    lds16(&BT[(size_t)(nb + ar1) * K + ac1], &Bs0[o1]);
    __syncthreads();

    for (int k0 = 0; k0 < K; k0 += 64) {
        lds16(&A [(size_t)(mb + ar0) * K + k0 + 32 + ac0], &As1[o0]);
        lds16(&A [(size_t)(mb + ar1) * K + k0 + 32 + ac1], &As1[o1]);
        lds16(&BT[(size_t)(nb + ar0) * K + k0 + 32 + ac0], &Bs1[o0]);
        lds16(&BT[(size_t)(nb + ar1) * K + k0 + 32 + ac1], &Bs1[o1]);
        {
            bf16x8 af[4], bfr[4];
#pragma unroll
            for (int i = 0; i < 4; i++)
                af[i] = *(const bf16x8*)&As0[(wm + i * 16 + l15) * 32 + quad * 8];
#pragma unroll
            for (int j = 0; j < 4; j++)
                bfr[j] = *(const bf16x8*)&Bs0[(wn + j * 16 + l15) * 32 + quad * 8];
#pragma unroll
            for (int i = 0; i < 4; i++)
#pragma unroll
                for (int j = 0; j < 4; j++)
                    acc[i][j] = mfma16(af[i], bfr[j], acc[i][j]);
        }
        __syncthreads();
        if (k0 + 64 < K) {
            lds16(&A [(size_t)(mb + ar0) * K + k0 + 64 + ac0], &As0[o0]);
            lds16(&A [(size_t)(mb + ar1) * K + k0 + 64 + ac1], &As0[o1]);
            lds16(&BT[(size_t)(nb + ar0) * K + k0 + 64 + ac0], &Bs0[o0]);
            lds16(&BT[(size_t)(nb + ar1) * K + k0 + 64 + ac1], &Bs0[o1]);
        }
        {
            bf16x8 af[4], bfr[4];
#pragma unroll
            for (int i = 0; i < 4; i++)
                af[i] = *(const bf16x8*)&As1[(wm + i * 16 + l15) * 32 + quad * 8];
#pragma unroll
            for (int j = 0; j < 4; j++)
                bfr[j] = *(const bf16x8*)&Bs1[(wn + j * 16 + l15) * 32 + quad * 8];
#pragma unroll
            for (int i = 0; i < 4; i++)
#pragma unroll
                for (int j = 0; j < 4; j++)
                    acc[i][j] = mfma16(af[i], bfr[j], acc[i][j]);
        }
        __syncthreads();
    }

    int reg = nb >> 9;   // 0=Q, 1=K, 2=V
    if (reg < 2) {
        bf16* C = reg ? Ck : Cq;
        float scl = reg ? 1.0f : QSCALE;
#pragma unroll
        for (int j = 0; j < 4; j++) {
            int n = nb + wn + j * 16 + l15;
            float bv = (float)bias[n];
            int nn = n & 511;
            int h = nn >> 6, dk = nn & 63;
#pragma unroll
            for (int i = 0; i < 4; i++) {
                int mBase = mb + wm + i * 16 + quad * 4;
#pragma unroll
                for (int r = 0; r < 4; r++) {
                    float v = (acc[i][j][r] + bv) * scl;
                    int m = mBase + r;
                    int b = m >> 11, s = m & (SEQ - 1);
                    C[((size_t)(b * NHEADS + h) * SEQ + s) * DHEAD + dk] = (bf16)v;
                }
            }
        }
    } else {
#pragma unroll
        for (int j = 0; j < 4; j++) {
            int nl = wn + j * 16 + l15;
            float bv = (float)bias[nb + nl];
#pragma unroll
            for (int i = 0; i < 4; i++) {
                int ml = wm + i * 16 + quad * 4;
                bf16x4 pk;
#pragma unroll
                for (int r = 0; r < 4; r++) pk[r] = (bf16)(acc[i][j][r] + bv);
                *(bf16x4*)&Ts[nl * 136 + ml] = pk;
            }
        }
        __syncthreads();
        int nl = tid >> 1, half = tid & 1;
        int nn = (nb + nl) & 511;
        int h = nn >> 6, dk = nn & 63;
        int bb = mb >> 11, s0 = mb & (SEQ - 1);
        bf16* dst = &Cv[((size_t)(bb * NHEADS + h) * DHEAD + dk) * SEQ + s0 + half * 64];
        const bf16* srcl = &Ts[nl * 136 + half * 64];
#pragma unroll
        for (int v = 0; v < 8; v++)
            *(uint4*)(dst + v * 8) = *(const uint4*)(srcl + v * 8);
    }
}

// ---------------------------------------------------------------------------
// Flash attention: grid (16, 32), block 256 = 4 waves, direct bf16 out.
// r22 swizzled-LDS staging (inverse-swizzled gload_lds source); r25: the
// per-step __syncthreads (vmcnt(0) semantics) replaced by counted
// vmcnt(4) + raw s_barrier -- next tile's 4 prefetch loads stay in
// flight across compute and the trailing barrier (T4). Last step
// vmcnt(0). sched_barrier(0) fences per rule #18.
// ---------------------------------------------------------------------------
__global__ __launch_bounds__(256) void attn_kernel(
        const bf16* __restrict__ Q, const bf16* __restrict__ K,
        const bf16* __restrict__ VT, bf16* __restrict__ Out) {
    __shared__ __align__(16) bf16 Ks[2][64 * 64];
    __shared__ __align__(16) bf16 Vs[2][64 * 64];
    __shared__ __align__(16) bf16 Pb[4][16 * 64];
    int tid  = threadIdx.x;
    int wid  = tid >> 6, lane = tid & 63;
    int quad = lane >> 4, l15 = lane & 15;

    int lin = blockIdx.y * 16 + blockIdx.x;        // grid is (16, 32)
    lin = (lin & 7) * 64 + (lin >> 3);             // bijective (512 = 8*64)
    int bh = lin >> 4;
    int qb = (lin & 15) * 128 + wid * 32;

    const bf16* Qh = Q  + (size_t)bh * SEQ * DHEAD;
    const bf16* Kh = K  + (size_t)bh * SEQ * DHEAD;
    const bf16* Vh = VT + (size_t)bh * DHEAD * SEQ;

    bf16x8 bQ0[2], bQ1[2];
#pragma unroll
    for (int c = 0; c < 2; c++) {
        const bf16* qp = &Qh[(qb + c * 16 + l15) * DHEAD + quad * 8];
        bQ0[c] = *(const bf16x8*)qp;
        bQ1[c] = *(const bf16x8*)(qp + 32);
    }

    bf16x8 vONE;
#pragma unroll
    for (int i = 0; i < 8; i++) vONE[i] = (bf16)1.0f;

    int srow = lane >> 3;
    int scol = ((lane & 7) ^ srow) << 3;   // global col offset (elems)
    int ldsb = wid * 1024;                 // wave's LDS base (elems)
    int krA = wid * 16 + srow, krB = krA + 8;

    int r7q = l15 & 7;
    int e0 = ((quad ^ r7q) << 3);
    int e1 = e0 ^ 32;

    f32x4 lacc[2] = {};
    f32x4 Oacc[2][4] = {};

    // prologue: stage tile 0 into buffer 0; drain fully once.
    lds16(&Kh[(size_t)krA * DHEAD + scol], &Ks[0][ldsb]);
    lds16(&Kh[(size_t)krB * DHEAD + scol], &Ks[0][ldsb + 512]);
    lds16(&Vh[(size_t)krA * SEQ + scol],   &Vs[0][ldsb]);
    lds16(&Vh[(size_t)krB * SEQ + scol],   &Vs[0][ldsb + 512]);
    asm volatile("s_waitcnt vmcnt(0)" ::: "memory");
    __builtin_amdgcn_sched_barrier(0);
    __builtin_amdgcn_s_barrier();
    __builtin_amdgcn_sched_barrier(0);

#define ATTN_STEP(CUR, NXT, KB, PF)                                          \
    {                                                                        \
        if (PF) {                                                            \
            lds16(&Kh[(size_t)((KB) + krA) * DHEAD + scol], &Ks[NXT][ldsb]); \
            lds16(&Kh[(size_t)((KB) + krB) * DHEAD + scol],                  \
                  &Ks[NXT][ldsb + 512]);                                     \
            lds16(&Vh[(size_t)krA * SEQ + (KB) + scol], &Vs[NXT][ldsb]);     \
            lds16(&Vh[(size_t)krB * SEQ + (KB) + scol],                      \
                  &Vs[NXT][ldsb + 512]);                                     \
        }                                                                    \
        bf16x8 aK0[4], aK1[4], bV0[4], bV1[4];                               \
        _Pragma("unroll")                                                    \
        for (int t = 0; t < 4; t++) {                                        \
            const bf16* kp = &Ks[CUR][(t * 16 + l15) * 64];                  \
            aK0[t] = *(const bf16x8*)(kp + e0);                              \
            aK1[t] = *(const bf16x8*)(kp + e1);                              \
            const bf16* vp = &Vs[CUR][(t * 16 + l15) * 64];                  \
            bV0[t] = *(const bf16x8*)(vp + e0);                              \
            bV1[t] = *(const bf16x8*)(vp + e1);                              \
        }                                                                    \
        _Pragma("unroll")                                                    \
        for (int c = 0; c < 2; c++) {                                        \
            __builtin_amdgcn_s_setprio(1);                                   \
            f32x4 st[4];                                                     \
            _Pragma("unroll")                                                \
            for (int t = 0; t < 4; t++) {                                    \
                f32x4 zv = {0.f, 0.f, 0.f, 0.f};                             \
                st[t] = mfma16(aK1[t], bQ1[c], mfma16(aK0[t], bQ0[c], zv));  \
            }                                                                \
            bf16* myP = Pb[wid];                                             \
            _Pragma("unroll")                                                \
            for (int t = 0; t < 4; t++) {                                    \
                bf16x4 pk;                                                   \
                _Pragma("unroll")                                            \
                for (int r = 0; r < 4; r++)                                  \
                    pk[r] = (bf16)__builtin_amdgcn_exp2f(                    \
                                fminf(st[t][r], 60.f));                      \
                int pch = ((2 * t + (quad >> 1)) ^ r7q) << 3;                \
                *(bf16x4*)&myP[l15 * 64 + pch + ((quad & 1) << 2)] = pk;     \
            }                                                                \
            bf16x8 aP0 = *(const bf16x8*)&myP[l15 * 64 + e0];                \
            bf16x8 aP1 = *(const bf16x8*)&myP[l15 * 64 + e1];                \
            _Pragma("unroll")                                                \
            for (int nt = 0; nt < 4; nt++)                                   \
                Oacc[c][nt] = mfma16(aP1, bV1[nt],                           \
                                     mfma16(aP0, bV0[nt], Oacc[c][nt]));     \
            lacc[c] = mfma16(aP1, vONE, mfma16(aP0, vONE, lacc[c]));         \
            __builtin_amdgcn_s_setprio(0);                                   \
        }                                                                    \
        /* T4: wait only for NEXT step's cur (issued above when PF); the  */ \
        /* 4 loads just issued stay in flight across the trailing barrier */ \
        if (PF) asm volatile("s_waitcnt vmcnt(4)" ::: "memory");             \
        else    asm volatile("s_waitcnt vmcnt(0)" ::: "memory");             \
        __builtin_amdgcn_sched_barrier(0);                                   \
        __builtin_amdgcn_s_barrier();                                        \
        __builtin_amdgcn_sched_barrier(0);                                   \
    }

    // NOTE on the counted wait: at each step top, up to 4 loads (this
    // step's prefetch) are issued; the PREVIOUS step's 4 completed before
    // we entered (its trailing vmcnt(4) counted this step's 4 as the
    // remaining in-flight ones). At the trailing wait here, outstanding =
    // this step's 4 only -> vmcnt(4) is a no-op for them but orders the
    // next step's reads AFTER the barrier; the NEXT step's trailing
    // vmcnt(4) is what guarantees this step's prefetch completed (it
    // allows only 4 outstanding = the next step's own prefetch).
    for (int it2 = 0; it2 < SEQ / 128; it2++) {
        ATTN_STEP(0, 1, (2 * it2 + 1) * 64, true);
        ATTN_STEP(1, 0, (2 * it2 + 2) * 64, (it2 + 1 < SEQ / 128));
    }
#undef ATTN_STEP

    int b = bh >> 3, hd = bh & 7;
#pragma unroll
    for (int c = 0; c < 2; c++) {
        float linv[4];
#pragma unroll
        for (int r = 0; r < 4; r++)
            linv[r] = 1.f / lacc[c][r];
#pragma unroll
        for (int nt = 0; nt < 4; nt++)
#pragma unroll
            for (int r = 0; r < 4; r++) {
                int s = qb + c * 16 + quad * 4 + r;
                Out[((size_t)(b * SEQ + s)) * DMODEL + hd * 64 + nt * 16 + l15]
                    = (bf16)(Oacc[c][nt][r] * linv[r]);
            }
    }
}

// ---------------------------------------------------------------------------
// Residual + LayerNorm (unbiased std ddof=1, eps added to std).
// ---------------------------------------------------------------------------
__global__ __launch_bounds__(256) void ln_kernel(
        const bf16* __restrict__ X, const bf16* __restrict__ T,
        const bf16* __restrict__ Al, const bf16* __restrict__ Bl,
        void* __restrict__ Out, int final_out) {
    int wid = threadIdx.x >> 6, lane = threadIdx.x & 63;
    int row = blockIdx.x * 4 + wid;
    const bf16* xr = X + (size_t)row * DMODEL;
    const bf16* tr = T + (size_t)row * DMODEL;
    bf16x8 xv = *(const bf16x8*)&xr[lane * 8];
    bf16x8 tv = *(const bf16x8*)&tr[lane * 8];
    float v[8];
#pragma unroll
    for (int i = 0; i < 8; i++) v[i] = (float)xv[i] + (float)tv[i];
    float sum = 0.f, sq = 0.f;
#pragma unroll
    for (int i = 0; i < 8; i++) { sum += v[i]; sq += v[i] * v[i]; }
#pragma unroll
    for (int m = 1; m < 64; m <<= 1) {
        sum += __shfl_xor(sum, m);
        sq  += __shfl_xor(sq,  m);
    }
    float mean = sum * (1.f / DMODEL);
    float var  = (sq - DMODEL * mean * mean) * (1.f / (DMODEL - 1));
    var = var > 0.f ? var : 0.f;
    float inv = 1.f / (sqrtf(var) + 1e-6f);
#pragma unroll
    for (int i = 0; i < 8; i++) {
        int c = lane * 8 + i;
        float yv = (float)Al[c] * (v[i] - mean) * inv + (float)Bl[c];
        yv = fminf(fmaxf(yv, -1e4f), 1e4f);
        size_t idx = (size_t)row * DMODEL + c;
        if (final_out) ((float*)Out)[idx] = yv;
        else           ((bf16*)Out)[idx]  = (bf16)yv;
    }
}

// ---------------------------------------------------------------------------
extern "C" void kernel_launch(void* const* d_in, const int* in_sizes, int n_in,
                              void* d_out, int out_size, void* d_ws, size_t ws_size,
                              hipStream_t stream) {
    if (ws_size < WS_NEED) {
        sentinel_kernel<<<1, 64, 0, stream>>>((bf16*)d_out);
        return;
    }

    const float* x  = (const float*)d_in[0];
    const float* wq = (const float*)d_in[1],  *bq = (const float*)d_in[2];
    const float* wk = (const float*)d_in[3],  *bk = (const float*)d_in[4];
    const float* wv = (const float*)d_in[5],  *bv = (const float*)d_in[6];
    const float* wo = (const float*)d_in[7],  *bo = (const float*)d_in[8];
    const float* w1 = (const float*)d_in[9],  *b1 = (const float*)d_in[10];
    const float* w2 = (const float*)d_in[11], *b2 = (const float*)d_in[12];
    const float* ln1a = (const float*)d_in[13], *ln1b = (const float*)d_in[14];
    const float* ln2a = (const float*)d_in[15], *ln2b = (const float*)d_in[16];

    char* ws = (char*)d_ws;
    bf16* wT   = (bf16*)(ws + 0);
    bf16* woT  = (bf16*)(ws + 1572864);
    bf16* w1T  = (bf16*)(ws + 2097152);
    bf16* w2T  = (bf16*)(ws + 4194304);
    bf16* xcv  = (bf16*)(ws + 6291456);
    bf16* prm  = (bf16*)(ws + 14680064);
    bf16* regA = (bf16*)(ws + 14696448);
    bf16* regB = (bf16*)(ws + 23085056);
    bf16* regC = (bf16*)(ws + 31473664);
    bf16* ff1  = (bf16*)(ws + 39862272);
    bf16* aout = (bf16*)d_out;   // scratch (fully overwritten by final LN)

    bf16 *pbq = prm, *pbo = prm + 1536;
    bf16 *pb1 = prm + 2048, *pb2 = prm + 4096;
    bf16 *pl1a = prm + 4608, *pl1b = prm + 5120;
    bf16 *pl2a = prm + 5632, *pl2b = prm + 6144;

    prep_kernel<<<7178, 256, 0, stream>>>(x, wq, wk, wv, wo, w1, w2,
                                          bq, bk, bv, bo, b1, b2,
                                          ln1a, ln1b, ln2a, ln2b,
                                          xcv, wT, w1T, w2T, prm);

    // fused QKV projection (Q pre-scaled by QSCALE; V^T coalesced epilogue)
    gemm_qkv<<<dim3(64, 12), 256, 0, stream>>>(xcv, wT, pbq,
                                               regA, regB, regC,
                                               MTOT, 3 * DMODEL, DMODEL);

    // attention -> d_out (scratch), direct bf16
    attn_kernel<<<dim3(SEQ / 128, NBATCH * NHEADS), 256, 0, stream>>>(
        regA, regB, regC, aout);

    // O-proj: aout -> t (regA); BM=64/BK=64
    gemm_bt64<false><<<dim3(128, 4), 256, 0, stream>>>(aout, woT, pbo, regA,
                                                       MTOT, DMODEL, DMODEL);

    // LN1: xcv + t -> y (regB)
    ln_kernel<<<MTOT / 4, 256, 0, stream>>>(xcv, regA, pl1a, pl1b, regB, 0);

    // FFN1: y -> ff1 (ReLU), 256^2 counted-vmcnt kernel
    gemm256<true><<<dim3(32, 8), 512, 0, stream>>>(regB, w1T, pb1, ff1,
                                                   MTOT, DFF, DMODEL);

    // FFN2: ff1 -> ff2 (regA)
    gemm_bt64<false><<<dim3(128, 4), 256, 0, stream>>>(ff1, w2T, pb2, regA,
                                                       MTOT, DMODEL, DFF);

    // LN2: y + ff2 -> out (fp32)
    ln_kernel<<<MTOT / 4, 256, 0, stream>>>(regB, regA, pl2a, pl2b, d_out, 1);
}

// Round 13
// 280.607 us; speedup vs baseline: 1.0241x; 1.0023x over previous
//
#include <hip/hip_runtime.h>
#include <hip/hip_bf16.h>

// ---------------------------------------------------------------------------
// EncoderBlock on MI355X (gfx950). Round 26.
// r25 post-mortem: attn T4 counted-vmcnt = null-to-negative (58.4 -> 60.8):
// at ring-2 depth the counted wait adds no in-flight depth over
// __syncthreads (m201's vmcnt(6) needs the 3-half-tile 8-phase stream;
// 2 buffers can't hold it). Reverted to r23-exact attn (plain barriers).
// r26 = stabilization at best-known config (~278 us): r22 attn staging
// (gload_lds, inverse-swizzled source), gemm256 ffn1 (r23), XCD-swizzled
// 2-phase gemm_bt64/gemm_qkv, + setprio hoisted to once per attn step.
// Session ledger: wins = LDS XOR-swizzle (r21, attn -6.5us, conflicts
// 7.34M->2.1M), GEMM XCD swizzle (r17, -3us). Nulls/regressions: split-K
// (r18/r24), reg-prefetch (r14/r16), 2-phase reorder (r19), full-row
// fusion (r20), coarse counted-vmcnt (r23), attn T4 (r25).
//
// ws layout (bytes), WS_NEED = 73416704, sentinel-guarded:
//   [0,        2097152)  wq|wk|wv|wo T (bf16)
//   [2097152,  4194304)  w1T
//   [4194304,  6291456)  w2T
//   [6291456, 14680064)  xcv: x as bf16 (8 MB)
//   [14680064,14696448)  small params (bf16)
//   A [14696448,23085056) qbuf -> t -> ff2      (8 MB)
//   B [23085056,31473664) kbuf -> y             (8 MB)
//   C [31473664,39862272) vT                    (8 MB)
//   F [39862272,73416704) ff1 (32 MB)
//   d_out                attn output scratch (bf16) -> final output (fp32)
// ---------------------------------------------------------------------------

typedef __bf16 bf16;
typedef __bf16 bf16x4 __attribute__((ext_vector_type(4)));
typedef __bf16 bf16x8 __attribute__((ext_vector_type(8)));
typedef float  f32x4  __attribute__((ext_vector_type(4)));

#define NBATCH 4
#define SEQ    2048
#define DMODEL 512
#define NHEADS 8
#define DHEAD  64
#define DFF    2048
#define MTOT   (NBATCH * SEQ)   // 8192
#define WS_NEED 73416704u
#define QSCALE (0.125f * 1.44269504f)   // 1/sqrt(dk) * log2(e), folded into Q

__device__ __forceinline__ f32x4 mfma16(bf16x8 a, bf16x8 b, f32x4 c) {
    return __builtin_amdgcn_mfma_f32_16x16x32_bf16(a, b, c, 0, 0, 0);
}

// async global->LDS, 16 B/lane. LDS dest = wave-uniform base + lane*16.
__device__ __forceinline__ void lds16(const bf16* g, bf16* l) {
    __builtin_amdgcn_global_load_lds(
        (const __attribute__((address_space(1))) void*)g,
        (__attribute__((address_space(3))) void*)l, 16, 0, 0);
}

__device__ __forceinline__ float scrub(float f) {
    return (fabsf(f) < 1e30f) ? f : 0.f;   // NaN/Inf -> 0 (no-op valid data)
}

// T1 XCD-chunked swizzle for 2D GEMM grids (requires gx*gy % 8 == 0).
__device__ __forceinline__ void xcd_swizzle(int BMv, int BNv, int& mb, int& nb) {
    int gx = gridDim.x, gy = gridDim.y;
    int lin = blockIdx.y * gx + blockIdx.x;
    int q = (gx * gy) >> 3;
    lin = (lin & 7) * q + (lin >> 3);
    int mbi = lin / gy, nbi = lin - mbi * gy;
    mb = mbi * BMv; nb = nbi * BNv;
}

__global__ void sentinel_kernel(bf16* out) {
    out[threadIdx.x] = (bf16)1000.0f;
}

// ---------------------------------------------------------------------------
// prep: x convert + small-param converts + all 6 weight transposes, ONE launch
// ---------------------------------------------------------------------------
__global__ __launch_bounds__(256) void prep_kernel(
        const float* x,
        const float* wq, const float* wk, const float* wv, const float* wo,
        const float* w1, const float* w2,
        const float* bq, const float* bk, const float* bv, const float* bo,
        const float* b1, const float* b2,
        const float* l1a, const float* l1b, const float* l2a, const float* l2b,
        bf16* __restrict__ xcv,
        bf16* __restrict__ wT, bf16* __restrict__ w1T, bf16* __restrict__ w2T,
        bf16* __restrict__ prm) {
    __shared__ bf16 tile[32][33];
    int b = blockIdx.x;
    if (b < 4096) {
        int i = (b * 256 + threadIdx.x) * 4;
        float4 f = *(const float4*)(x + i);
        bf16x4 o = {(bf16)scrub(f.x), (bf16)scrub(f.y),
                    (bf16)scrub(f.z), (bf16)scrub(f.w)};
        *(bf16x4*)(xcv + i) = o;
        return;
    }
    if (b < 4106) {
        int pb = b - 4096;
        const float* srcs[10] = {bq, bk, bv, bo, b1, b2, l1a, l1b, l2a, l2b};
        const int len[10] = {512,512,512,512,2048,512,512,512,512,512};
        const int dst[10] = {0,512,1024,1536,2048,4096,4608,5120,5632,6144};
        const float* s = srcs[pb];
        bf16* d = prm + dst[pb];
        for (int i = threadIdx.x; i < len[pb]; i += 256)
            d[i] = (bf16)scrub(s[i]);
        return;
    }
    const float* in; bf16* out; int K, N, bx, by;
    if (b < 5130) {
        int idx = b - 4106, z = idx >> 8, rem = idx & 255;
        const float* srcs[4] = {wq, wk, wv, wo};
        in = srcs[z]; out = wT + (size_t)z * 262144;
        K = 512; N = 512; bx = rem & 15; by = rem >> 4;
    } else if (b < 6154) {
        int idx = b - 5130;
        in = w1; out = w1T; K = 512; N = 2048; bx = idx & 63; by = idx >> 6;
    } else {
        int idx = b - 6154;
        in = w2; out = w2T; K = 2048; N = 512; bx = idx & 15; by = idx >> 4;
    }
    int tx = threadIdx.x & 31, ty = threadIdx.x >> 5;
    int n0 = bx * 32, k0 = by * 32;
#pragma unroll
    for (int i = 0; i < 4; i++) {
        int kl = ty * 4 + i;
        tile[kl][tx] = (bf16)scrub(in[(size_t)(k0 + kl) * N + n0 + tx]);
    }
    __syncthreads();
#pragma unroll
    for (int i = 0; i < 4; i++) {
        int nl = ty * 4 + i;
        out[(size_t)(n0 + nl) * K + k0 + tx] = tile[tx][nl];
    }
}

// ---------------------------------------------------------------------------
// 256x256 GEMM (FFN1), 8 waves, BK=64, ring-2 LDS, counted vmcnt, T2
// swizzle via pre-swizzled gload_lds source, setprio. r23-verified.
// ---------------------------------------------------------------------------
template <bool RELU>
__global__ __launch_bounds__(512) void gemm256(
        const bf16* __restrict__ A, const bf16* __restrict__ BT,
        const bf16* __restrict__ bias, bf16* __restrict__ Cout,
        int M, int N, int K) {
    __shared__ __align__(16) bf16 Abuf[2][256 * 64];
    __shared__ __align__(16) bf16 Bbuf[2][256 * 64];

    int tid  = threadIdx.x;
    int w    = tid >> 6, lane = tid & 63;
    int quad = lane >> 4, l15 = lane & 15;
    int mb, nb;
    xcd_swizzle(256, 256, mb, nb);
    int wm = (w >> 2) * 128, wn = (w & 3) * 64;

    int srow   = lane >> 3;
    int gchunk = ((lane & 7) ^ srow) << 3;   // inverse-swizzled source col
    int rb0    = w * 32;
    int sw     = l15 & 7;                    // frag-read swizzle (= row&7)

    f32x4 acc[8][4] = {};
    int NT = K >> 6;

#define STAGE256(BUF, KO)                                                    \
    _Pragma("unroll")                                                        \
    for (int a = 0; a < 4; a++) {                                            \
        int rb = rb0 + a * 8;                                                \
        lds16(&A [(size_t)(mb + rb + srow) * K + (KO) + gchunk],             \
              &Abuf[BUF][rb * 64]);                                          \
        lds16(&BT[(size_t)(nb + rb + srow) * K + (KO) + gchunk],             \
              &Bbuf[BUF][rb * 64]);                                          \
    }

    STAGE256(0, 0);

    for (int k = 0; k < NT; k++) {
        if (k + 1 < NT) {
            STAGE256((k + 1) & 1, (k + 1) << 6);
            asm volatile("s_waitcnt vmcnt(8)" ::: "memory");
        } else {
            asm volatile("s_waitcnt vmcnt(0)" ::: "memory");
        }
        __builtin_amdgcn_sched_barrier(0);
        __builtin_amdgcn_s_barrier();
        __builtin_amdgcn_sched_barrier(0);

        const bf16* Ab = &Abuf[k & 1][0];
        const bf16* Bb = &Bbuf[k & 1][0];
        __builtin_amdgcn_s_setprio(1);
#pragma unroll
        for (int ks = 0; ks < 2; ks++) {
            int ch = (((ks << 2) + quad) ^ sw) << 3;
            bf16x8 bfr[4];
#pragma unroll
            for (int j = 0; j < 4; j++)
                bfr[j] = *(const bf16x8*)&Bb[(wn + j * 16 + l15) * 64 + ch];
#pragma unroll
            for (int i = 0; i < 8; i++) {
                bf16x8 af = *(const bf16x8*)&Ab[(wm + i * 16 + l15) * 64 + ch];
#pragma unroll
                for (int j = 0; j < 4; j++)
                    acc[i][j] = mfma16(af, bfr[j], acc[i][j]);
            }
        }
        __builtin_amdgcn_s_setprio(0);
        __builtin_amdgcn_sched_barrier(0);
        __builtin_amdgcn_s_barrier();
        __builtin_amdgcn_sched_barrier(0);
    }
#undef STAGE256

#pragma unroll
    for (int j = 0; j < 4; j++) {
        int n = nb + wn + j * 16 + l15;
        float bv = (float)bias[n];
#pragma unroll
        for (int i = 0; i < 8; i++) {
            int mBase = mb + wm + i * 16 + quad * 4;
#pragma unroll
            for (int r = 0; r < 4; r++) {
                float v = acc[i][j][r] + bv;
                if (RELU) v = v > 0.f ? v : 0.f;
                Cout[(size_t)(mBase + r) * N + n] = (bf16)v;
            }
        }
    }
}

// ---------------------------------------------------------------------------
// BM=64, BN=128 GEMM, 2-phase stage-ahead pipeline. For O-proj / FFN2.
// ---------------------------------------------------------------------------
template <bool RELU>
__global__ __launch_bounds__(256) void gemm_bt64(
        const bf16* __restrict__ A, const bf16* __restrict__ BT,
        const bf16* __restrict__ bias, bf16* __restrict__ Cout,
        int M, int N, int K) {
    constexpr int BM = 64, BN = 128;
    __shared__ __align__(16) bf16 As0[BM * 32], As1[BM * 32];
    __shared__ __align__(16) bf16 Bs0[BN * 32], Bs1[BN * 32];

    int tid  = threadIdx.x;
    int wid  = tid >> 6, lane = tid & 63;
    int quad = lane >> 4, l15 = lane & 15;
    int mb, nb;
    xcd_swizzle(BM, BN, mb, nb);
    int wm = (wid >> 1) * 32, wn = (wid & 1) * 64;

    f32x4 acc[2][4] = {};

    int cA = wid * 64 + lane;
    int arA = cA >> 2, acA = (cA & 3) * 8;
    int cB0 = wid * 128 + lane, cB1 = cB0 + 64;
    int br0 = cB0 >> 2, bc0 = (cB0 & 3) * 8;
    int br1 = cB1 >> 2, bc1 = (cB1 & 3) * 8;

    lds16(&A [(size_t)(mb + arA) * K + acA], &As0[wid * 512]);
    lds16(&BT[(size_t)(nb + br0) * K + bc0], &Bs0[wid * 1024]);
    lds16(&BT[(size_t)(nb + br1) * K + bc1], &Bs0[wid * 1024 + 512]);
    __syncthreads();

    for (int k0 = 0; k0 < K; k0 += 64) {
        lds16(&A [(size_t)(mb + arA) * K + k0 + 32 + acA], &As1[wid * 512]);
        lds16(&BT[(size_t)(nb + br0) * K + k0 + 32 + bc0], &Bs1[wid * 1024]);
        lds16(&BT[(size_t)(nb + br1) * K + k0 + 32 + bc1], &Bs1[wid * 1024 + 512]);
        {
            bf16x8 a0[2], b0[4];
#pragma unroll
            for (int i = 0; i < 2; i++)
                a0[i] = *(const bf16x8*)&As0[(wm + i * 16 + l15) * 32 + quad * 8];
#pragma unroll
            for (int j = 0; j < 4; j++)
                b0[j] = *(const bf16x8*)&Bs0[(wn + j * 16 + l15) * 32 + quad * 8];
#pragma unroll
            for (int i = 0; i < 2; i++)
#pragma unroll
                for (int j = 0; j < 4; j++)
                    acc[i][j] = mfma16(a0[i], b0[j], acc[i][j]);
        }
        __syncthreads();
        if (k0 + 64 < K) {
            lds16(&A [(size_t)(mb + arA) * K + k0 + 64 + acA], &As0[wid * 512]);
            lds16(&BT[(size_t)(nb + br0) * K + k0 + 64 + bc0], &Bs0[wid * 1024]);
            lds16(&BT[(size_t)(nb + br1) * K + k0 + 64 + bc1], &Bs0[wid * 1024 + 512]);
        }
        {
            bf16x8 a1[2], b1[4];
#pragma unroll
            for (int i = 0; i < 2; i++)
                a1[i] = *(const bf16x8*)&As1[(wm + i * 16 + l15) * 32 + quad * 8];
#pragma unroll
            for (int j = 0; j < 4; j++)
                b1[j] = *(const bf16x8*)&Bs1[(wn + j * 16 + l15) * 32 + quad * 8];
#pragma unroll
            for (int i = 0; i < 2; i++)
#pragma unroll
                for (int j = 0; j < 4; j++)
                    acc[i][j] = mfma16(a1[i], b1[j], acc[i][j]);
        }
        __syncthreads();
    }

#pragma unroll
    for (int j = 0; j < 4; j++) {
        int n = nb + wn + j * 16 + l15;
        float bv = (float)bias[n];
#pragma unroll
        for (int i = 0; i < 2; i++) {
            int mBase = mb + wm + i * 16 + quad * 4;
#pragma unroll
            for (int r = 0; r < 4; r++) {
                float v = acc[i][j][r] + bv;
                if (RELU) v = v > 0.f ? v : 0.f;
                Cout[(size_t)(mBase + r) * N + n] = (bf16)v;
            }
        }
    }
}

// ---------------------------------------------------------------------------
// Fused QKV GEMM, 2-phase stage-ahead pipeline; region 0 -> Q*(QSCALE),
// 1 -> K, 2 -> V^T via LDS-transposed coalesced epilogue. XCD-swizzled.
// ---------------------------------------------------------------------------
__global__ __launch_bounds__(256) void gemm_qkv(
        const bf16* __restrict__ A, const bf16* __restrict__ BT,
        const bf16* __restrict__ bias,
        bf16* __restrict__ Cq, bf16* __restrict__ Ck, bf16* __restrict__ Cv,
        int M, int N, int K) {
    constexpr int BM = 128, BN = 128;
    __shared__ __align__(16) bf16 As0[BM * 32], As1[BM * 32];
    __shared__ __align__(16) bf16 Bs0[BN * 32], Bs1[BN * 32];
    __shared__ __align__(16) bf16 Ts[128 * 136];

    int tid  = threadIdx.x;
    int wid  = tid >> 6, lane = tid & 63;
    int quad = lane >> 4, l15 = lane & 15;
    int mb, nb;
    xcd_swizzle(BM, BN, mb, nb);
    int wm = (wid >> 1) * 64, wn = (wid & 1) * 64;

    f32x4 acc[4][4] = {};

    int c0 = wid * 128 + lane, c1 = c0 + 64;
    int ar0 = c0 >> 2, ac0 = (c0 & 3) * 8;
    int ar1 = c1 >> 2, ac1 = (c1 & 3) * 8;
    int o0 = wid * 1024, o1 = wid * 1024 + 512;

    lds16(&A [(size_t)(mb + ar0) * K + ac0], &As0[o0]);
    lds16(&A [(size_t)(mb + ar1) * K + ac1], &As0[o1]);
    lds16(&BT[(size_t)(nb + ar0) * K + ac0], &Bs0[o0]);
    lds16(&BT[(size_t)(nb + ar1) * K + ac1], &Bs0[o1]);
    __syncthreads();

    for (int k0 = 0; k0 < K; k0 += 64) {
        lds16(&A [(size_t)(mb + ar0) * K + k0 + 32 + ac0], &As1[o0]);
        lds16(&A [(size_t)(mb + ar1) * K + k0 + 32 + ac1], &As1[o1]);
        lds16(&BT[(size_t)(nb + ar0) * K + k0 + 32 + ac0], &Bs1[o0]);
        lds16(&BT[(size_t)(nb + ar1) * K + k0 + 32 + ac1], &Bs1[o1]);
        {
            bf16x8 af[4], bfr[4];
#pragma unroll
            for (int i = 0; i < 4; i++)
                af[i] = *(const bf16x8*)&As0[(wm + i * 16 + l15) * 32 + quad * 8];
#pragma unroll
            for (int j = 0; j < 4; j++)
                bfr[j] = *(const bf16x8*)&Bs0[(wn + j * 16 + l15) * 32 + quad * 8];
#pragma unroll
            for (int i = 0; i < 4; i++)
#pragma unroll
                for (int j = 0; j < 4; j++)
                    acc[i][j] = mfma16(af[i], bfr[j], acc[i][j]);
        }
        __syncthreads();
        if (k0 + 64 < K) {
            lds16(&A [(size_t)(mb + ar0) * K + k0 + 64 + ac0], &As0[o0]);
            lds16(&A [(size_t)(mb + ar1) * K + k0 + 64 + ac1], &As0[o1]);
            lds16(&BT[(size_t)(nb + ar0) * K + k0 + 64 + ac0], &Bs0[o0]);
            lds16(&BT[(size_t)(nb + ar1) * K + k0 + 64 + ac1], &Bs0[o1]);
        }
        {
            bf16x8 af[4], bfr[4];
#pragma unroll
            for (int i = 0; i < 4; i++)
                af[i] = *(const bf16x8*)&As1[(wm + i * 16 + l15) * 32 + quad * 8];
#pragma unroll
            for (int j = 0; j < 4; j++)
                bfr[j] = *(const bf16x8*)&Bs1[(wn + j * 16 + l15) * 32 + quad * 8];
#pragma unroll
            for (int i = 0; i < 4; i++)
#pragma unroll
                for (int j = 0; j < 4; j++)
                    acc[i][j] = mfma16(af[i], bfr[j], acc[i][j]);
        }
        __syncthreads();
    }

    int reg = nb >> 9;   // 0=Q, 1=K, 2=V
    if (reg < 2) {
        bf16* C = reg ? Ck : Cq;
        float scl = reg ? 1.0f : QSCALE;
#pragma unroll
        for (int j = 0; j < 4; j++) {
            int n = nb + wn + j * 16 + l15;
            float bv = (float)bias[n];
            int nn = n & 511;
            int h = nn >> 6, dk = nn & 63;
#pragma unroll
            for (int i = 0; i < 4; i++) {
                int mBase = mb + wm + i * 16 + quad * 4;
#pragma unroll
                for (int r = 0; r < 4; r++) {
                    float v = (acc[i][j][r] + bv) * scl;
                    int m = mBase + r;
                    int b = m >> 11, s = m & (SEQ - 1);
                    C[((size_t)(b * NHEADS + h) * SEQ + s) * DHEAD + dk] = (bf16)v;
                }
            }
        }
    } else {
#pragma unroll
        for (int j = 0; j < 4; j++) {
            int nl = wn + j * 16 + l15;
            float bv = (float)bias[nb + nl];
#pragma unroll
            for (int i = 0; i < 4; i++) {
                int ml = wm + i * 16 + quad * 4;
                bf16x4 pk;
#pragma unroll
                for (int r = 0; r < 4; r++) pk[r] = (bf16)(acc[i][j][r] + bv);
                *(bf16x4*)&Ts[nl * 136 + ml] = pk;
            }
        }
        __syncthreads();
        int nl = tid >> 1, half = tid & 1;
        int nn = (nb + nl) & 511;
        int h = nn >> 6, dk = nn & 63;
        int bb = mb >> 11, s0 = mb & (SEQ - 1);
        bf16* dst = &Cv[((size_t)(bb * NHEADS + h) * DHEAD + dk) * SEQ + s0 + half * 64];
        const bf16* srcl = &Ts[nl * 136 + half * 64];
#pragma unroll
        for (int v = 0; v < 8; v++)
            *(uint4*)(dst + v * 8) = *(const uint4*)(srcl + v * 8);
    }
}

// ---------------------------------------------------------------------------
// Flash attention: grid (16, 32), block 256 = 4 waves, direct bf16 out.
// r22/r23 structure: swizzled LDS via inverse-swizzled gload_lds source,
// conflict-free frag reads, l-row via MFMA ones-trick, XCD swizzle, plain
// __syncthreads per step (counted-vmcnt reverted, r25 null). setprio
// hoisted to once per step.
// ---------------------------------------------------------------------------
__global__ __launch_bounds__(256) void attn_kernel(
        const bf16* __restrict__ Q, const bf16* __restrict__ K,
        const bf16* __restrict__ VT, bf16* __restrict__ Out) {
    __shared__ __align__(16) bf16 Ks[2][64 * 64];
    __shared__ __align__(16) bf16 Vs[2][64 * 64];
    __shared__ __align__(16) bf16 Pb[4][16 * 64];
    int tid  = threadIdx.x;
    int wid  = tid >> 6, lane = tid & 63;
    int quad = lane >> 4, l15 = lane & 15;

    int lin = blockIdx.y * 16 + blockIdx.x;        // grid is (16, 32)
    lin = (lin & 7) * 64 + (lin >> 3);             // bijective (512 = 8*64)
    int bh = lin >> 4;
    int qb = (lin & 15) * 128 + wid * 32;

    const bf16* Qh = Q  + (size_t)bh * SEQ * DHEAD;
    const bf16* Kh = K  + (size_t)bh * SEQ * DHEAD;
    const bf16* Vh = VT + (size_t)bh * DHEAD * SEQ;

    bf16x8 bQ0[2], bQ1[2];
#pragma unroll
    for (int c = 0; c < 2; c++) {
        const bf16* qp = &Qh[(qb + c * 16 + l15) * DHEAD + quad * 8];
        bQ0[c] = *(const bf16x8*)qp;
        bQ1[c] = *(const bf16x8*)(qp + 32);
    }

    bf16x8 vONE;
#pragma unroll
    for (int i = 0; i < 8; i++) vONE[i] = (bf16)1.0f;

    int srow = lane >> 3;
    int scol = ((lane & 7) ^ srow) << 3;   // global col offset (elems)
    int ldsb = wid * 1024;                 // wave's LDS base (elems)
    int krA = wid * 16 + srow, krB = krA + 8;

    int r7q = l15 & 7;
    int e0 = ((quad ^ r7q) << 3);
    int e1 = e0 ^ 32;

    f32x4 lacc[2] = {};
    f32x4 Oacc[2][4] = {};

    lds16(&Kh[(size_t)krA * DHEAD + scol], &Ks[0][ldsb]);
    lds16(&Kh[(size_t)krB * DHEAD + scol], &Ks[0][ldsb + 512]);
    lds16(&Vh[(size_t)krA * SEQ + scol],   &Vs[0][ldsb]);
    lds16(&Vh[(size_t)krB * SEQ + scol],   &Vs[0][ldsb + 512]);
    __syncthreads();

#define ATTN_STEP(CUR, NXT, KB, PF)                                          \
    {                                                                        \
        if (PF) {                                                            \
            lds16(&Kh[(size_t)((KB) + krA) * DHEAD + scol], &Ks[NXT][ldsb]); \
            lds16(&Kh[(size_t)((KB) + krB) * DHEAD + scol],                  \
                  &Ks[NXT][ldsb + 512]);                                     \
            lds16(&Vh[(size_t)krA * SEQ + (KB) + scol], &Vs[NXT][ldsb]);     \
            lds16(&Vh[(size_t)krB * SEQ + (KB) + scol],                      \
                  &Vs[NXT][ldsb + 512]);                                     \
        }                                                                    \
        bf16x8 aK0[4], aK1[4], bV0[4], bV1[4];                               \
        _Pragma("unroll")                                                    \
        for (int t = 0; t < 4; t++) {                                        \
            const bf16* kp = &Ks[CUR][(t * 16 + l15) * 64];                  \
            aK0[t] = *(const bf16x8*)(kp + e0);                              \
            aK1[t] = *(const bf16x8*)(kp + e1);                              \
            const bf16* vp = &Vs[CUR][(t * 16 + l15) * 64];                  \
            bV0[t] = *(const bf16x8*)(vp + e0);                              \
            bV1[t] = *(const bf16x8*)(vp + e1);                              \
        }                                                                    \
        __builtin_amdgcn_s_setprio(1);                                       \
        _Pragma("unroll")                                                    \
        for (int c = 0; c < 2; c++) {                                        \
            f32x4 st[4];                                                     \
            _Pragma("unroll")                                                \
            for (int t = 0; t < 4; t++) {                                    \
                f32x4 zv = {0.f, 0.f, 0.f, 0.f};                             \
                st[t] = mfma16(aK1[t], bQ1[c], mfma16(aK0[t], bQ0[c], zv));  \
            }                                                                \
            bf16* myP = Pb[wid];                                             \
            _Pragma("unroll")                                                \
            for (int t = 0; t < 4; t++) {                                    \
                bf16x4 pk;                                                   \
                _Pragma("unroll")                                            \
                for (int r = 0; r < 4; r++)                                  \
                    pk[r] = (bf16)__builtin_amdgcn_exp2f(                    \
                                fminf(st[t][r], 60.f));                      \
                int pch = ((2 * t + (quad >> 1)) ^ r7q) << 3;                \
                *(bf16x4*)&myP[l15 * 64 + pch + ((quad & 1) << 2)] = pk;     \
            }                                                                \
            bf16x8 aP0 = *(const bf16x8*)&myP[l15 * 64 + e0];                \
            bf16x8 aP1 = *(const bf16x8*)&myP[l15 * 64 + e1];                \
            _Pragma("unroll")                                                \
            for (int nt = 0; nt < 4; nt++)                                   \
                Oacc[c][nt] = mfma16(aP1, bV1[nt],                           \
                                     mfma16(aP0, bV0[nt], Oacc[c][nt]));     \
            lacc[c] = mfma16(aP1, vONE, mfma16(aP0, vONE, lacc[c]));         \
        }                                                                    \
        __builtin_amdgcn_s_setprio(0);                                       \
        __syncthreads();                                                     \
    }

    for (int it2 = 0; it2 < SEQ / 128; it2++) {
        ATTN_STEP(0, 1, (2 * it2 + 1) * 64, true);
        ATTN_STEP(1, 0, (2 * it2 + 2) * 64, (it2 + 1 < SEQ / 128));
    }
#undef ATTN_STEP

    int b = bh >> 3, hd = bh & 7;
#pragma unroll
    for (int c = 0; c < 2; c++) {
        float linv[4];
#pragma unroll
        for (int r = 0; r < 4; r++)
            linv[r] = 1.f / lacc[c][r];
#pragma unroll
        for (int nt = 0; nt < 4; nt++)
#pragma unroll
            for (int r = 0; r < 4; r++) {
                int s = qb + c * 16 + quad * 4 + r;
                Out[((size_t)(b * SEQ + s)) * DMODEL + hd * 64 + nt * 16 + l15]
                    = (bf16)(Oacc[c][nt][r] * linv[r]);
            }
    }
}

// ---------------------------------------------------------------------------
// Residual + LayerNorm (unbiased std ddof=1, eps added to std).
// ---------------------------------------------------------------------------
__global__ __launch_bounds__(256) void ln_kernel(
        const bf16* __restrict__ X, const bf16* __restrict__ T,
        const bf16* __restrict__ Al, const bf16* __restrict__ Bl,
        void* __restrict__ Out, int final_out) {
    int wid = threadIdx.x >> 6, lane = threadIdx.x & 63;
    int row = blockIdx.x * 4 + wid;
    const bf16* xr = X + (size_t)row * DMODEL;
    const bf16* tr = T + (size_t)row * DMODEL;
    bf16x8 xv = *(const bf16x8*)&xr[lane * 8];
    bf16x8 tv = *(const bf16x8*)&tr[lane * 8];
    float v[8];
#pragma unroll
    for (int i = 0; i < 8; i++) v[i] = (float)xv[i] + (float)tv[i];
    float sum = 0.f, sq = 0.f;
#pragma unroll
    for (int i = 0; i < 8; i++) { sum += v[i]; sq += v[i] * v[i]; }
#pragma unroll
    for (int m = 1; m < 64; m <<= 1) {
        sum += __shfl_xor(sum, m);
        sq  += __shfl_xor(sq,  m);
    }
    float mean = sum * (1.f / DMODEL);
    float var  = (sq - DMODEL * mean * mean) * (1.f / (DMODEL - 1));
    var = var > 0.f ? var : 0.f;
    float inv = 1.f / (sqrtf(var) + 1e-6f);
#pragma unroll
    for (int i = 0; i < 8; i++) {
        int c = lane * 8 + i;
        float yv = (float)Al[c] * (v[i] - mean) * inv + (float)Bl[c];
        yv = fminf(fmaxf(yv, -1e4f), 1e4f);
        size_t idx = (size_t)row * DMODEL + c;
        if (final_out) ((float*)Out)[idx] = yv;
        else           ((bf16*)Out)[idx]  = (bf16)yv;
    }
}

// ---------------------------------------------------------------------------
extern "C" void kernel_launch(void* const* d_in, const int* in_sizes, int n_in,
                              void* d_out, int out_size, void* d_ws, size_t ws_size,
                              hipStream_t stream) {
    if (ws_size < WS_NEED) {
        sentinel_kernel<<<1, 64, 0, stream>>>((bf16*)d_out);
        return;
    }

    const float* x  = (const float*)d_in[0];
    const float* wq = (const float*)d_in[1],  *bq = (const float*)d_in[2];
    const float* wk = (const float*)d_in[3],  *bk = (const float*)d_in[4];
    const float* wv = (const float*)d_in[5],  *bv = (const float*)d_in[6];
    const float* wo = (const float*)d_in[7],  *bo = (const float*)d_in[8];
    const float* w1 = (const float*)d_in[9],  *b1 = (const float*)d_in[10];
    const float* w2 = (const float*)d_in[11], *b2 = (const float*)d_in[12];
    const float* ln1a = (const float*)d_in[13], *ln1b = (const float*)d_in[14];
    const float* ln2a = (const float*)d_in[15], *ln2b = (const float*)d_in[16];

    char* ws = (char*)d_ws;
    bf16* wT   = (bf16*)(ws + 0);
    bf16* woT  = (bf16*)(ws + 1572864);
    bf16* w1T  = (bf16*)(ws + 2097152);
    bf16* w2T  = (bf16*)(ws + 4194304);
    bf16* xcv  = (bf16*)(ws + 6291456);
    bf16* prm  = (bf16*)(ws + 14680064);
    bf16* regA = (bf16*)(ws + 14696448);
    bf16* regB = (bf16*)(ws + 23085056);
    bf16* regC = (bf16*)(ws + 31473664);
    bf16* ff1  = (bf16*)(ws + 39862272);
    bf16* aout = (bf16*)d_out;   // scratch (fully overwritten by final LN)

    bf16 *pbq = prm, *pbo = prm + 1536;
    bf16 *pb1 = prm + 2048, *pb2 = prm + 4096;
    bf16 *pl1a = prm + 4608, *pl1b = prm + 5120;
    bf16 *pl2a = prm + 5632, *pl2b = prm + 6144;

    prep_kernel<<<7178, 256, 0, stream>>>(x, wq, wk, wv, wo, w1, w2,
                                          bq, bk, bv, bo, b1, b2,
                                          ln1a, ln1b, ln2a, ln2b,
                                          xcv, wT, w1T, w2T, prm);

    // fused QKV projection (Q pre-scaled by QSCALE; V^T coalesced epilogue)
    gemm_qkv<<<dim3(64, 12), 256, 0, stream>>>(xcv, wT, pbq,
                                               regA, regB, regC,
                                               MTOT, 3 * DMODEL, DMODEL);

    // attention -> d_out (scratch), direct bf16
    attn_kernel<<<dim3(SEQ / 128, NBATCH * NHEADS), 256, 0, stream>>>(
        regA, regB, regC, aout);

    // O-proj: aout -> t (regA); BM=64/BK=64
    gemm_bt64<false><<<dim3(128, 4), 256, 0, stream>>>(aout, woT, pbo, regA,
                                                       MTOT, DMODEL, DMODEL);

    // LN1: xcv + t -> y (regB)
    ln_kernel<<<MTOT / 4, 256, 0, stream>>>(xcv, regA, pl1a, pl1b, regB, 0);

    // FFN1: y -> ff1 (ReLU), 256^2 counted-vmcnt kernel
    gemm256<true><<<dim3(32, 8), 512, 0, stream>>>(regB, w1T, pb1, ff1,
                                                   MTOT, DFF, DMODEL);

    // FFN2: ff1 -> ff2 (regA)
    gemm_bt64<false><<<dim3(128, 4), 256, 0, stream>>>(ff1, w2T, pb2, regA,
                                                       MTOT, DMODEL, DFF);

    // LN2: y + ff2 -> out (fp32)
    ln_kernel<<<MTOT / 4, 256, 0, stream>>>(regB, regA, pl2a, pl2b, d_out, 1);
}

// Round 14
// 278.960 us; speedup vs baseline: 1.0301x; 1.0059x over previous
//
#include <hip/hip_runtime.h>
#include <hip/hip_bf16.h>

// ---------------------------------------------------------------------------
// EncoderBlock on MI355X (gfx950). Round 27.
// r26 post-mortem: 280.6 vs r23's 278.9 with IDENTICAL GEMMs -> total
// noise band ~ +/-2us; r21/r23/r26 are one plateau at ~279+/-2. Not a
// hardware roofline (no pipe >60%); the documented exits (8-phase fine
// interleave, m214 8-warp attn) are blind-port race risks (m152) -- the
// 8-phase half-tile residency ledger cannot be reconstructed safely from
// prose. r27 = last safe mechanism lever: attn KVBLK 64->128 (two 64x64
// sub-tiles per buffer, identical swizzle per sub-tile) -> 16 steps
// instead of 32 -> HALF the barrier convoys, and each drain covers its 8
// staged loads with a double-length compute phase. LDS 40->72KB (still
// 2 blocks/CU). Frag regs reused across sub-tiles (VGPR unchanged).
//
// ws layout (bytes), WS_NEED = 73416704, sentinel-guarded:
//   [0,        2097152)  wq|wk|wv|wo T (bf16)
//   [2097152,  4194304)  w1T
//   [4194304,  6291456)  w2T
//   [6291456, 14680064)  xcv: x as bf16 (8 MB)
//   [14680064,14696448)  small params (bf16)
//   A [14696448,23085056) qbuf -> t -> ff2      (8 MB)
//   B [23085056,31473664) kbuf -> y             (8 MB)
//   C [31473664,39862272) vT                    (8 MB)
//   F [39862272,73416704) ff1 (32 MB)
//   d_out                attn output scratch (bf16) -> final output (fp32)
// ---------------------------------------------------------------------------

typedef __bf16 bf16;
typedef __bf16 bf16x4 __attribute__((ext_vector_type(4)));
typedef __bf16 bf16x8 __attribute__((ext_vector_type(8)));
typedef float  f32x4  __attribute__((ext_vector_type(4)));

#define NBATCH 4
#define SEQ    2048
#define DMODEL 512
#define NHEADS 8
#define DHEAD  64
#define DFF    2048
#define MTOT   (NBATCH * SEQ)   // 8192
#define WS_NEED 73416704u
#define QSCALE (0.125f * 1.44269504f)   // 1/sqrt(dk) * log2(e), folded into Q

__device__ __forceinline__ f32x4 mfma16(bf16x8 a, bf16x8 b, f32x4 c) {
    return __builtin_amdgcn_mfma_f32_16x16x32_bf16(a, b, c, 0, 0, 0);
}

// async global->LDS, 16 B/lane. LDS dest = wave-uniform base + lane*16.
__device__ __forceinline__ void lds16(const bf16* g, bf16* l) {
    __builtin_amdgcn_global_load_lds(
        (const __attribute__((address_space(1))) void*)g,
        (__attribute__((address_space(3))) void*)l, 16, 0, 0);
}

__device__ __forceinline__ float scrub(float f) {
    return (fabsf(f) < 1e30f) ? f : 0.f;   // NaN/Inf -> 0 (no-op valid data)
}

// T1 XCD-chunked swizzle for 2D GEMM grids (requires gx*gy % 8 == 0).
__device__ __forceinline__ void xcd_swizzle(int BMv, int BNv, int& mb, int& nb) {
    int gx = gridDim.x, gy = gridDim.y;
    int lin = blockIdx.y * gx + blockIdx.x;
    int q = (gx * gy) >> 3;
    lin = (lin & 7) * q + (lin >> 3);
    int mbi = lin / gy, nbi = lin - mbi * gy;
    mb = mbi * BMv; nb = nbi * BNv;
}

__global__ void sentinel_kernel(bf16* out) {
    out[threadIdx.x] = (bf16)1000.0f;
}

// ---------------------------------------------------------------------------
// prep: x convert + small-param converts + all 6 weight transposes, ONE launch
// ---------------------------------------------------------------------------
__global__ __launch_bounds__(256) void prep_kernel(
        const float* x,
        const float* wq, const float* wk, const float* wv, const float* wo,
        const float* w1, const float* w2,
        const float* bq, const float* bk, const float* bv, const float* bo,
        const float* b1, const float* b2,
        const float* l1a, const float* l1b, const float* l2a, const float* l2b,
        bf16* __restrict__ xcv,
        bf16* __restrict__ wT, bf16* __restrict__ w1T, bf16* __restrict__ w2T,
        bf16* __restrict__ prm) {
    __shared__ bf16 tile[32][33];
    int b = blockIdx.x;
    if (b < 4096) {
        int i = (b * 256 + threadIdx.x) * 4;
        float4 f = *(const float4*)(x + i);
        bf16x4 o = {(bf16)scrub(f.x), (bf16)scrub(f.y),
                    (bf16)scrub(f.z), (bf16)scrub(f.w)};
        *(bf16x4*)(xcv + i) = o;
        return;
    }
    if (b < 4106) {
        int pb = b - 4096;
        const float* srcs[10] = {bq, bk, bv, bo, b1, b2, l1a, l1b, l2a, l2b};
        const int len[10] = {512,512,512,512,2048,512,512,512,512,512};
        const int dst[10] = {0,512,1024,1536,2048,4096,4608,5120,5632,6144};
        const float* s = srcs[pb];
        bf16* d = prm + dst[pb];
        for (int i = threadIdx.x; i < len[pb]; i += 256)
            d[i] = (bf16)scrub(s[i]);
        return;
    }
    const float* in; bf16* out; int K, N, bx, by;
    if (b < 5130) {
        int idx = b - 4106, z = idx >> 8, rem = idx & 255;
        const float* srcs[4] = {wq, wk, wv, wo};
        in = srcs[z]; out = wT + (size_t)z * 262144;
        K = 512; N = 512; bx = rem & 15; by = rem >> 4;
    } else if (b < 6154) {
        int idx = b - 5130;
        in = w1; out = w1T; K = 512; N = 2048; bx = idx & 63; by = idx >> 6;
    } else {
        int idx = b - 6154;
        in = w2; out = w2T; K = 2048; N = 512; bx = idx & 15; by = idx >> 4;
    }
    int tx = threadIdx.x & 31, ty = threadIdx.x >> 5;
    int n0 = bx * 32, k0 = by * 32;
#pragma unroll
    for (int i = 0; i < 4; i++) {
        int kl = ty * 4 + i;
        tile[kl][tx] = (bf16)scrub(in[(size_t)(k0 + kl) * N + n0 + tx]);
    }
    __syncthreads();
#pragma unroll
    for (int i = 0; i < 4; i++) {
        int nl = ty * 4 + i;
        out[(size_t)(n0 + nl) * K + k0 + tx] = tile[tx][nl];
    }
}

// ---------------------------------------------------------------------------
// 256x256 GEMM (FFN1), 8 waves, BK=64, ring-2 LDS, counted vmcnt, T2
// swizzle via pre-swizzled gload_lds source, setprio. r23-verified.
// ---------------------------------------------------------------------------
template <bool RELU>
__global__ __launch_bounds__(512) void gemm256(
        const bf16* __restrict__ A, const bf16* __restrict__ BT,
        const bf16* __restrict__ bias, bf16* __restrict__ Cout,
        int M, int N, int K) {
    __shared__ __align__(16) bf16 Abuf[2][256 * 64];
    __shared__ __align__(16) bf16 Bbuf[2][256 * 64];

    int tid  = threadIdx.x;
    int w    = tid >> 6, lane = tid & 63;
    int quad = lane >> 4, l15 = lane & 15;
    int mb, nb;
    xcd_swizzle(256, 256, mb, nb);
    int wm = (w >> 2) * 128, wn = (w & 3) * 64;

    int srow   = lane >> 3;
    int gchunk = ((lane & 7) ^ srow) << 3;   // inverse-swizzled source col
    int rb0    = w * 32;
    int sw     = l15 & 7;                    // frag-read swizzle (= row&7)

    f32x4 acc[8][4] = {};
    int NT = K >> 6;

#define STAGE256(BUF, KO)                                                    \
    _Pragma("unroll")                                                        \
    for (int a = 0; a < 4; a++) {                                            \
        int rb = rb0 + a * 8;                                                \
        lds16(&A [(size_t)(mb + rb + srow) * K + (KO) + gchunk],             \
              &Abuf[BUF][rb * 64]);                                          \
        lds16(&BT[(size_t)(nb + rb + srow) * K + (KO) + gchunk],             \
              &Bbuf[BUF][rb * 64]);                                          \
    }

    STAGE256(0, 0);

    for (int k = 0; k < NT; k++) {
        if (k + 1 < NT) {
            STAGE256((k + 1) & 1, (k + 1) << 6);
            asm volatile("s_waitcnt vmcnt(8)" ::: "memory");
        } else {
            asm volatile("s_waitcnt vmcnt(0)" ::: "memory");
        }
        __builtin_amdgcn_sched_barrier(0);
        __builtin_amdgcn_s_barrier();
        __builtin_amdgcn_sched_barrier(0);

        const bf16* Ab = &Abuf[k & 1][0];
        const bf16* Bb = &Bbuf[k & 1][0];
        __builtin_amdgcn_s_setprio(1);
#pragma unroll
        for (int ks = 0; ks < 2; ks++) {
            int ch = (((ks << 2) + quad) ^ sw) << 3;
            bf16x8 bfr[4];
#pragma unroll
            for (int j = 0; j < 4; j++)
                bfr[j] = *(const bf16x8*)&Bb[(wn + j * 16 + l15) * 64 + ch];
#pragma unroll
            for (int i = 0; i < 8; i++) {
                bf16x8 af = *(const bf16x8*)&Ab[(wm + i * 16 + l15) * 64 + ch];
#pragma unroll
                for (int j = 0; j < 4; j++)
                    acc[i][j] = mfma16(af, bfr[j], acc[i][j]);
            }
        }
        __builtin_amdgcn_s_setprio(0);
        __builtin_amdgcn_sched_barrier(0);
        __builtin_amdgcn_s_barrier();
        __builtin_amdgcn_sched_barrier(0);
    }
#undef STAGE256

#pragma unroll
    for (int j = 0; j < 4; j++) {
        int n = nb + wn + j * 16 + l15;
        float bv = (float)bias[n];
#pragma unroll
        for (int i = 0; i < 8; i++) {
            int mBase = mb + wm + i * 16 + quad * 4;
#pragma unroll
            for (int r = 0; r < 4; r++) {
                float v = acc[i][j][r] + bv;
                if (RELU) v = v > 0.f ? v : 0.f;
                Cout[(size_t)(mBase + r) * N + n] = (bf16)v;
            }
        }
    }
}

// ---------------------------------------------------------------------------
// BM=64, BN=128 GEMM, 2-phase stage-ahead pipeline. For O-proj / FFN2.
// ---------------------------------------------------------------------------
template <bool RELU>
__global__ __launch_bounds__(256) void gemm_bt64(
        const bf16* __restrict__ A, const bf16* __restrict__ BT,
        const bf16* __restrict__ bias, bf16* __restrict__ Cout,
        int M, int N, int K) {
    constexpr int BM = 64, BN = 128;
    __shared__ __align__(16) bf16 As0[BM * 32], As1[BM * 32];
    __shared__ __align__(16) bf16 Bs0[BN * 32], Bs1[BN * 32];

    int tid  = threadIdx.x;
    int wid  = tid >> 6, lane = tid & 63;
    int quad = lane >> 4, l15 = lane & 15;
    int mb, nb;
    xcd_swizzle(BM, BN, mb, nb);
    int wm = (wid >> 1) * 32, wn = (wid & 1) * 64;

    f32x4 acc[2][4] = {};

    int cA = wid * 64 + lane;
    int arA = cA >> 2, acA = (cA & 3) * 8;
    int cB0 = wid * 128 + lane, cB1 = cB0 + 64;
    int br0 = cB0 >> 2, bc0 = (cB0 & 3) * 8;
    int br1 = cB1 >> 2, bc1 = (cB1 & 3) * 8;

    lds16(&A [(size_t)(mb + arA) * K + acA], &As0[wid * 512]);
    lds16(&BT[(size_t)(nb + br0) * K + bc0], &Bs0[wid * 1024]);
    lds16(&BT[(size_t)(nb + br1) * K + bc1], &Bs0[wid * 1024 + 512]);
    __syncthreads();

    for (int k0 = 0; k0 < K; k0 += 64) {
        lds16(&A [(size_t)(mb + arA) * K + k0 + 32 + acA], &As1[wid * 512]);
        lds16(&BT[(size_t)(nb + br0) * K + k0 + 32 + bc0], &Bs1[wid * 1024]);
        lds16(&BT[(size_t)(nb + br1) * K + k0 + 32 + bc1], &Bs1[wid * 1024 + 512]);
        {
            bf16x8 a0[2], b0[4];
#pragma unroll
            for (int i = 0; i < 2; i++)
                a0[i] = *(const bf16x8*)&As0[(wm + i * 16 + l15) * 32 + quad * 8];
#pragma unroll
            for (int j = 0; j < 4; j++)
                b0[j] = *(const bf16x8*)&Bs0[(wn + j * 16 + l15) * 32 + quad * 8];
#pragma unroll
            for (int i = 0; i < 2; i++)
#pragma unroll
                for (int j = 0; j < 4; j++)
                    acc[i][j] = mfma16(a0[i], b0[j], acc[i][j]);
        }
        __syncthreads();
        if (k0 + 64 < K) {
            lds16(&A [(size_t)(mb + arA) * K + k0 + 64 + acA], &As0[wid * 512]);
            lds16(&BT[(size_t)(nb + br0) * K + k0 + 64 + bc0], &Bs0[wid * 1024]);
            lds16(&BT[(size_t)(nb + br1) * K + k0 + 64 + bc1], &Bs0[wid * 1024 + 512]);
        }
        {
            bf16x8 a1[2], b1[4];
#pragma unroll
            for (int i = 0; i < 2; i++)
                a1[i] = *(const bf16x8*)&As1[(wm + i * 16 + l15) * 32 + quad * 8];
#pragma unroll
            for (int j = 0; j < 4; j++)
                b1[j] = *(const bf16x8*)&Bs1[(wn + j * 16 + l15) * 32 + quad * 8];
#pragma unroll
            for (int i = 0; i < 2; i++)
#pragma unroll
                for (int j = 0; j < 4; j++)
                    acc[i][j] = mfma16(a1[i], b1[j], acc[i][j]);
        }
        __syncthreads();
    }

#pragma unroll
    for (int j = 0; j < 4; j++) {
        int n = nb + wn + j * 16 + l15;
        float bv = (float)bias[n];
#pragma unroll
        for (int i = 0; i < 2; i++) {
            int mBase = mb + wm + i * 16 + quad * 4;
#pragma unroll
            for (int r = 0; r < 4; r++) {
                float v = acc[i][j][r] + bv;
                if (RELU) v = v > 0.f ? v : 0.f;
                Cout[(size_t)(mBase + r) * N + n] = (bf16)v;
            }
        }
    }
}

// ---------------------------------------------------------------------------
// Fused QKV GEMM, 2-phase stage-ahead pipeline; region 0 -> Q*(QSCALE),
// 1 -> K, 2 -> V^T via LDS-transposed coalesced epilogue. XCD-swizzled.
// ---------------------------------------------------------------------------
__global__ __launch_bounds__(256) void gemm_qkv(
        const bf16* __restrict__ A, const bf16* __restrict__ BT,
        const bf16* __restrict__ bias,
        bf16* __restrict__ Cq, bf16* __restrict__ Ck, bf16* __restrict__ Cv,
        int M, int N, int K) {
    constexpr int BM = 128, BN = 128;
    __shared__ __align__(16) bf16 As0[BM * 32], As1[BM * 32];
    __shared__ __align__(16) bf16 Bs0[BN * 32], Bs1[BN * 32];
    __shared__ __align__(16) bf16 Ts[128 * 136];

    int tid  = threadIdx.x;
    int wid  = tid >> 6, lane = tid & 63;
    int quad = lane >> 4, l15 = lane & 15;
    int mb, nb;
    xcd_swizzle(BM, BN, mb, nb);
    int wm = (wid >> 1) * 64, wn = (wid & 1) * 64;

    f32x4 acc[4][4] = {};

    int c0 = wid * 128 + lane, c1 = c0 + 64;
    int ar0 = c0 >> 2, ac0 = (c0 & 3) * 8;
    int ar1 = c1 >> 2, ac1 = (c1 & 3) * 8;
    int o0 = wid * 1024, o1 = wid * 1024 + 512;

    lds16(&A [(size_t)(mb + ar0) * K + ac0], &As0[o0]);
    lds16(&A [(size_t)(mb + ar1) * K + ac1], &As0[o1]);
    lds16(&BT[(size_t)(nb + ar0) * K + ac0], &Bs0[o0]);
    lds16(&BT[(size_t)(nb + ar1) * K + ac1], &Bs0[o1]);
    __syncthreads();

    for (int k0 = 0; k0 < K; k0 += 64) {
        lds16(&A [(size_t)(mb + ar0) * K + k0 + 32 + ac0], &As1[o0]);
        lds16(&A [(size_t)(mb + ar1) * K + k0 + 32 + ac1], &As1[o1]);
        lds16(&BT[(size_t)(nb + ar0) * K + k0 + 32 + ac0], &Bs1[o0]);
        lds16(&BT[(size_t)(nb + ar1) * K + k0 + 32 + ac1], &Bs1[o1]);
        {
            bf16x8 af[4], bfr[4];
#pragma unroll
            for (int i = 0; i < 4; i++)
                af[i] = *(const bf16x8*)&As0[(wm + i * 16 + l15) * 32 + quad * 8];
#pragma unroll
            for (int j = 0; j < 4; j++)
                bfr[j] = *(const bf16x8*)&Bs0[(wn + j * 16 + l15) * 32 + quad * 8];
#pragma unroll
            for (int i = 0; i < 4; i++)
#pragma unroll
                for (int j = 0; j < 4; j++)
                    acc[i][j] = mfma16(af[i], bfr[j], acc[i][j]);
        }
        __syncthreads();
        if (k0 + 64 < K) {
            lds16(&A [(size_t)(mb + ar0) * K + k0 + 64 + ac0], &As0[o0]);
            lds16(&A [(size_t)(mb + ar1) * K + k0 + 64 + ac1], &As0[o1]);
            lds16(&BT[(size_t)(nb + ar0) * K + k0 + 64 + ac0], &Bs0[o0]);
            lds16(&BT[(size_t)(nb + ar1) * K + k0 + 64 + ac1], &Bs0[o1]);
        }
        {
            bf16x8 af[4], bfr[4];
#pragma unroll
            for (int i = 0; i < 4; i++)
                af[i] = *(const bf16x8*)&As1[(wm + i * 16 + l15) * 32 + quad * 8];
#pragma unroll
            for (int j = 0; j < 4; j++)
                bfr[j] = *(const bf16x8*)&Bs1[(wn + j * 16 + l15) * 32 + quad * 8];
#pragma unroll
            for (int i = 0; i < 4; i++)
#pragma unroll
                for (int j = 0; j < 4; j++)
                    acc[i][j] = mfma16(af[i], bfr[j], acc[i][j]);
        }
        __syncthreads();
    }

    int reg = nb >> 9;   // 0=Q, 1=K, 2=V
    if (reg < 2) {
        bf16* C = reg ? Ck : Cq;
        float scl = reg ? 1.0f : QSCALE;
#pragma unroll
        for (int j = 0; j < 4; j++) {
            int n = nb + wn + j * 16 + l15;
            float bv = (float)bias[n];
            int nn = n & 511;
            int h = nn >> 6, dk = nn & 63;
#pragma unroll
            for (int i = 0; i < 4; i++) {
                int mBase = mb + wm + i * 16 + quad * 4;
#pragma unroll
                for (int r = 0; r < 4; r++) {
                    float v = (acc[i][j][r] + bv) * scl;
                    int m = mBase + r;
                    int b = m >> 11, s = m & (SEQ - 1);
                    C[((size_t)(b * NHEADS + h) * SEQ + s) * DHEAD + dk] = (bf16)v;
                }
            }
        }
    } else {
#pragma unroll
        for (int j = 0; j < 4; j++) {
            int nl = wn + j * 16 + l15;
            float bv = (float)bias[nb + nl];
#pragma unroll
            for (int i = 0; i < 4; i++) {
                int ml = wm + i * 16 + quad * 4;
                bf16x4 pk;
#pragma unroll
                for (int r = 0; r < 4; r++) pk[r] = (bf16)(acc[i][j][r] + bv);
                *(bf16x4*)&Ts[nl * 136 + ml] = pk;
            }
        }
        __syncthreads();
        int nl = tid >> 1, half = tid & 1;
        int nn = (nb + nl) & 511;
        int h = nn >> 6, dk = nn & 63;
        int bb = mb >> 11, s0 = mb & (SEQ - 1);
        bf16* dst = &Cv[((size_t)(bb * NHEADS + h) * DHEAD + dk) * SEQ + s0 + half * 64];
        const bf16* srcl = &Ts[nl * 136 + half * 64];
#pragma unroll
        for (int v = 0; v < 8; v++)
            *(uint4*)(dst + v * 8) = *(const uint4*)(srcl + v * 8);
    }
}

// ---------------------------------------------------------------------------
// Flash attention: grid (16, 32), block 256 = 4 waves, direct bf16 out.
// r27: KVBLK=128 -- each double-buffered step holds TWO 64x64 sub-tiles of
// K and V (identical r21/r22 swizzled layout per sub-tile; zero new layout
// math). 16 steps instead of 32 -> half the barrier convoys; each drain's
// 8 staged loads covered by a double compute phase. Staging remains
// gload_lds with inverse-swizzled source; frag reads conflict-free;
// l-row via MFMA ones-trick; setprio around the step compute; XCD swizzle.
// ---------------------------------------------------------------------------
__global__ __launch_bounds__(256) void attn_kernel(
        const bf16* __restrict__ Q, const bf16* __restrict__ K,
        const bf16* __restrict__ VT, bf16* __restrict__ Out) {
    __shared__ __align__(16) bf16 Ks[2][2][64 * 64];
    __shared__ __align__(16) bf16 Vs[2][2][64 * 64];
    __shared__ __align__(16) bf16 Pb[4][16 * 64];
    int tid  = threadIdx.x;
    int wid  = tid >> 6, lane = tid & 63;
    int quad = lane >> 4, l15 = lane & 15;

    int lin = blockIdx.y * 16 + blockIdx.x;        // grid is (16, 32)
    lin = (lin & 7) * 64 + (lin >> 3);             // bijective (512 = 8*64)
    int bh = lin >> 4;
    int qb = (lin & 15) * 128 + wid * 32;

    const bf16* Qh = Q  + (size_t)bh * SEQ * DHEAD;
    const bf16* Kh = K  + (size_t)bh * SEQ * DHEAD;
    const bf16* Vh = VT + (size_t)bh * DHEAD * SEQ;

    bf16x8 bQ0[2], bQ1[2];
#pragma unroll
    for (int c = 0; c < 2; c++) {
        const bf16* qp = &Qh[(qb + c * 16 + l15) * DHEAD + quad * 8];
        bQ0[c] = *(const bf16x8*)qp;
        bQ1[c] = *(const bf16x8*)(qp + 32);
    }

    bf16x8 vONE;
#pragma unroll
    for (int i = 0; i < 8; i++) vONE[i] = (bf16)1.0f;

    int srow = lane >> 3;
    int scol = ((lane & 7) ^ srow) << 3;   // global col offset (elems)
    int ldsb = wid * 1024;                 // wave's LDS base (elems)
    int krA = wid * 16 + srow, krB = krA + 8;

    int r7q = l15 & 7;
    int e0 = ((quad ^ r7q) << 3);
    int e1 = e0 ^ 32;

    f32x4 lacc[2] = {};
    f32x4 Oacc[2][4] = {};

    // prologue: stage 128-key tile 0 (both sub-tiles) into buffer 0
#pragma unroll
    for (int sb = 0; sb < 2; sb++) {
        lds16(&Kh[(size_t)(sb * 64 + krA) * DHEAD + scol], &Ks[0][sb][ldsb]);
        lds16(&Kh[(size_t)(sb * 64 + krB) * DHEAD + scol], &Ks[0][sb][ldsb + 512]);
        lds16(&Vh[(size_t)krA * SEQ + sb * 64 + scol],     &Vs[0][sb][ldsb]);
        lds16(&Vh[(size_t)krB * SEQ + sb * 64 + scol],     &Vs[0][sb][ldsb + 512]);
    }
    __syncthreads();

// one 64-key sub-tile compute body (identical to r26's step compute)
#define ATTN_SUB(CUR, SB)                                                    \
    {                                                                        \
        bf16x8 aK0[4], aK1[4], bV0[4], bV1[4];                               \
        _Pragma("unroll")                                                    \
        for (int t = 0; t < 4; t++) {                                        \
            const bf16* kp = &Ks[CUR][SB][(t * 16 + l15) * 64];              \
            aK0[t] = *(const bf16x8*)(kp + e0);                              \
            aK1[t] = *(const bf16x8*)(kp + e1);                              \
            const bf16* vp = &Vs[CUR][SB][(t * 16 + l15) * 64];              \
            bV0[t] = *(const bf16x8*)(vp + e0);                              \
            bV1[t] = *(const bf16x8*)(vp + e1);                              \
        }                                                                    \
        _Pragma("unroll")                                                    \
        for (int c = 0; c < 2; c++) {                                        \
            f32x4 st[4];                                                     \
            _Pragma("unroll")                                                \
            for (int t = 0; t < 4; t++) {                                    \
                f32x4 zv = {0.f, 0.f, 0.f, 0.f};                             \
                st[t] = mfma16(aK1[t], bQ1[c], mfma16(aK0[t], bQ0[c], zv));  \
            }                                                                \
            bf16* myP = Pb[wid];                                             \
            _Pragma("unroll")                                                \
            for (int t = 0; t < 4; t++) {                                    \
                bf16x4 pk;                                                   \
                _Pragma("unroll")                                            \
                for (int r = 0; r < 4; r++)                                  \
                    pk[r] = (bf16)__builtin_amdgcn_exp2f(                    \
                                fminf(st[t][r], 60.f));                      \
                int pch = ((2 * t + (quad >> 1)) ^ r7q) << 3;                \
                *(bf16x4*)&myP[l15 * 64 + pch + ((quad & 1) << 2)] = pk;     \
            }                                                                \
            bf16x8 aP0 = *(const bf16x8*)&myP[l15 * 64 + e0];                \
            bf16x8 aP1 = *(const bf16x8*)&myP[l15 * 64 + e1];                \
            _Pragma("unroll")                                                \
            for (int nt = 0; nt < 4; nt++)                                   \
                Oacc[c][nt] = mfma16(aP1, bV1[nt],                           \
                                     mfma16(aP0, bV0[nt], Oacc[c][nt]));     \
            lacc[c] = mfma16(aP1, vONE, mfma16(aP0, vONE, lacc[c]));         \
        }                                                                    \
    }

// full 128-key step: prefetch next 128-key tile, compute both sub-tiles
#define ATTN_STEP(CUR, NXT, KB, PF)                                          \
    {                                                                        \
        if (PF) {                                                            \
            _Pragma("unroll")                                                \
            for (int sb = 0; sb < 2; sb++) {                                 \
                lds16(&Kh[(size_t)((KB) + sb * 64 + krA) * DHEAD + scol],    \
                      &Ks[NXT][sb][ldsb]);                                   \
                lds16(&Kh[(size_t)((KB) + sb * 64 + krB) * DHEAD + scol],    \
                      &Ks[NXT][sb][ldsb + 512]);                             \
                lds16(&Vh[(size_t)krA * SEQ + (KB) + sb * 64 + scol],        \
                      &Vs[NXT][sb][ldsb]);                                   \
                lds16(&Vh[(size_t)krB * SEQ + (KB) + sb * 64 + scol],        \
                      &Vs[NXT][sb][ldsb + 512]);                             \
            }                                                                \
        }                                                                    \
        __builtin_amdgcn_s_setprio(1);                                       \
        ATTN_SUB(CUR, 0);                                                    \
        ATTN_SUB(CUR, 1);                                                    \
        __builtin_amdgcn_s_setprio(0);                                       \
        __syncthreads();                                                     \
    }

    for (int it2 = 0; it2 < SEQ / 256; it2++) {
        ATTN_STEP(0, 1, (2 * it2 + 1) * 128, true);
        ATTN_STEP(1, 0, (2 * it2 + 2) * 128, (it2 + 1 < SEQ / 256));
    }
#undef ATTN_STEP
#undef ATTN_SUB

    int b = bh >> 3, hd = bh & 7;
#pragma unroll
    for (int c = 0; c < 2; c++) {
        float linv[4];
#pragma unroll
        for (int r = 0; r < 4; r++)
            linv[r] = 1.f / lacc[c][r];
#pragma unroll
        for (int nt = 0; nt < 4; nt++)
#pragma unroll
            for (int r = 0; r < 4; r++) {
                int s = qb + c * 16 + quad * 4 + r;
                Out[((size_t)(b * SEQ + s)) * DMODEL + hd * 64 + nt * 16 + l15]
                    = (bf16)(Oacc[c][nt][r] * linv[r]);
            }
    }
}

// ---------------------------------------------------------------------------
// Residual + LayerNorm (unbiased std ddof=1, eps added to std).
// ---------------------------------------------------------------------------
__global__ __launch_bounds__(256) void ln_kernel(
        const bf16* __restrict__ X, const bf16* __restrict__ T,
        const bf16* __restrict__ Al, const bf16* __restrict__ Bl,
        void* __restrict__ Out, int final_out) {
    int wid = threadIdx.x >> 6, lane = threadIdx.x & 63;
    int row = blockIdx.x * 4 + wid;
    const bf16* xr = X + (size_t)row * DMODEL;
    const bf16* tr = T + (size_t)row * DMODEL;
    bf16x8 xv = *(const bf16x8*)&xr[lane * 8];
    bf16x8 tv = *(const bf16x8*)&tr[lane * 8];
    float v[8];
#pragma unroll
    for (int i = 0; i < 8; i++) v[i] = (float)xv[i] + (float)tv[i];
    float sum = 0.f, sq = 0.f;
#pragma unroll
    for (int i = 0; i < 8; i++) { sum += v[i]; sq += v[i] * v[i]; }
#pragma unroll
    for (int m = 1; m < 64; m <<= 1) {
        sum += __shfl_xor(sum, m);
        sq  += __shfl_xor(sq,  m);
    }
    float mean = sum * (1.f / DMODEL);
    float var  = (sq - DMODEL * mean * mean) * (1.f / (DMODEL - 1));
    var = var > 0.f ? var : 0.f;
    float inv = 1.f / (sqrtf(var) + 1e-6f);
#pragma unroll
    for (int i = 0; i < 8; i++) {
        int c = lane * 8 + i;
        float yv = (float)Al[c] * (v[i] - mean) * inv + (float)Bl[c];
        yv = fminf(fmaxf(yv, -1e4f), 1e4f);
        size_t idx = (size_t)row * DMODEL + c;
        if (final_out) ((float*)Out)[idx] = yv;
        else           ((bf16*)Out)[idx]  = (bf16)yv;
    }
}

// ---------------------------------------------------------------------------
extern "C" void kernel_launch(void* const* d_in, const int* in_sizes, int n_in,
                              void* d_out, int out_size, void* d_ws, size_t ws_size,
                              hipStream_t stream) {
    if (ws_size < WS_NEED) {
        sentinel_kernel<<<1, 64, 0, stream>>>((bf16*)d_out);
        return;
    }

    const float* x  = (const float*)d_in[0];
    const float* wq = (const float*)d_in[1],  *bq = (const float*)d_in[2];
    const float* wk = (const float*)d_in[3],  *bk = (const float*)d_in[4];
    const float* wv = (const float*)d_in[5],  *bv = (const float*)d_in[6];
    const float* wo = (const float*)d_in[7],  *bo = (const float*)d_in[8];
    const float* w1 = (const float*)d_in[9],  *b1 = (const float*)d_in[10];
    const float* w2 = (const float*)d_in[11], *b2 = (const float*)d_in[12];
    const float* ln1a = (const float*)d_in[13], *ln1b = (const float*)d_in[14];
    const float* ln2a = (const float*)d_in[15], *ln2b = (const float*)d_in[16];

    char* ws = (char*)d_ws;
    bf16* wT   = (bf16*)(ws + 0);
    bf16* woT  = (bf16*)(ws + 1572864);
    bf16* w1T  = (bf16*)(ws + 2097152);
    bf16* w2T  = (bf16*)(ws + 4194304);
    bf16* xcv  = (bf16*)(ws + 6291456);
    bf16* prm  = (bf16*)(ws + 14680064);
    bf16* regA = (bf16*)(ws + 14696448);
    bf16* regB = (bf16*)(ws + 23085056);
    bf16* regC = (bf16*)(ws + 31473664);
    bf16* ff1  = (bf16*)(ws + 39862272);
    bf16* aout = (bf16*)d_out;   // scratch (fully overwritten by final LN)

    bf16 *pbq = prm, *pbo = prm + 1536;
    bf16 *pb1 = prm + 2048, *pb2 = prm + 4096;
    bf16 *pl1a = prm + 4608, *pl1b = prm + 5120;
    bf16 *pl2a = prm + 5632, *pl2b = prm + 6144;

    prep_kernel<<<7178, 256, 0, stream>>>(x, wq, wk, wv, wo, w1, w2,
                                          bq, bk, bv, bo, b1, b2,
                                          ln1a, ln1b, ln2a, ln2b,
                                          xcv, wT, w1T, w2T, prm);

    // fused QKV projection (Q pre-scaled by QSCALE; V^T coalesced epilogue)
    gemm_qkv<<<dim3(64, 12), 256, 0, stream>>>(xcv, wT, pbq,
                                               regA, regB, regC,
                                               MTOT, 3 * DMODEL, DMODEL);

    // attention -> d_out (scratch), direct bf16
    attn_kernel<<<dim3(SEQ / 128, NBATCH * NHEADS), 256, 0, stream>>>(
        regA, regB, regC, aout);

    // O-proj: aout -> t (regA); BM=64/BK=64
    gemm_bt64<false><<<dim3(128, 4), 256, 0, stream>>>(aout, woT, pbo, regA,
                                                       MTOT, DMODEL, DMODEL);

    // LN1: xcv + t -> y (regB)
    ln_kernel<<<MTOT / 4, 256, 0, stream>>>(xcv, regA, pl1a, pl1b, regB, 0);

    // FFN1: y -> ff1 (ReLU), 256^2 counted-vmcnt kernel
    gemm256<true><<<dim3(32, 8), 512, 0, stream>>>(regB, w1T, pb1, ff1,
                                                   MTOT, DFF, DMODEL);

    // FFN2: ff1 -> ff2 (regA)
    gemm_bt64<false><<<dim3(128, 4), 256, 0, stream>>>(ff1, w2T, pb2, regA,
                                                       MTOT, DMODEL, DFF);

    // LN2: y + ff2 -> out (fp32)
    ln_kernel<<<MTOT / 4, 256, 0, stream>>>(regB, regA, pl2a, pl2b, d_out, 1);
}

// Round 15
// 276.101 us; speedup vs baseline: 1.0408x; 1.0104x over previous
//
#include <hip/hip_runtime.h>
#include <hip/hip_bf16.h>

// ---------------------------------------------------------------------------
// EncoderBlock on MI355X (gfx950). Round 28.
// r27 post-mortem: attn KVBLK=128 -> 57.0us (best; convoy halving worth
// ~1.3us -> attn now dependency-bound). Totals: r21=277.9 (gemm_bt ffn1),
// r23/r27=278.9/279.0 (gemm256 ffn1) -- the FFN1 kernel choice is the
// only config difference; gemm256 never beat gemm_bt (r23 null).
// r28 = component-wise best-of-session: r27 attn (KVBLK=128, swizzled
// gload_lds staging) + r21 GEMM set (gemm_bt 128^2 ffn1, gemm_bt64
// oproj/ffn2, gemm_qkv; all XCD-swizzled 2-phase stage-ahead).
// Session ledger: wins = LDS XOR-swizzle (r21), GEMM XCD swizzle (r17),
// KVBLK=128 (r27, ~1.3us attn). Nulls/regressions: split-K (r18/r24),
// reg-prefetch (r14/r16), 2-phase reorder (r19), full-row fusion (r20),
// coarse counted-vmcnt (r23), attn T4 (r25). Remaining exits (8-phase
// fine interleave, m214 8-warp attn) = blind-port race risk, declined.
//
// ws layout (bytes), WS_NEED = 73416704, sentinel-guarded:
//   [0,        2097152)  wq|wk|wv|wo T (bf16)
//   [2097152,  4194304)  w1T
//   [4194304,  6291456)  w2T
//   [6291456, 14680064)  xcv: x as bf16 (8 MB)
//   [14680064,14696448)  small params (bf16)
//   A [14696448,23085056) qbuf -> t -> ff2      (8 MB)
//   B [23085056,31473664) kbuf -> y             (8 MB)
//   C [31473664,39862272) vT                    (8 MB)
//   F [39862272,73416704) ff1 (32 MB)
//   d_out                attn output scratch (bf16) -> final output (fp32)
// ---------------------------------------------------------------------------

typedef __bf16 bf16;
typedef __bf16 bf16x4 __attribute__((ext_vector_type(4)));
typedef __bf16 bf16x8 __attribute__((ext_vector_type(8)));
typedef float  f32x4  __attribute__((ext_vector_type(4)));

#define NBATCH 4
#define SEQ    2048
#define DMODEL 512
#define NHEADS 8
#define DHEAD  64
#define DFF    2048
#define MTOT   (NBATCH * SEQ)   // 8192
#define WS_NEED 73416704u
#define QSCALE (0.125f * 1.44269504f)   // 1/sqrt(dk) * log2(e), folded into Q

__device__ __forceinline__ f32x4 mfma16(bf16x8 a, bf16x8 b, f32x4 c) {
    return __builtin_amdgcn_mfma_f32_16x16x32_bf16(a, b, c, 0, 0, 0);
}

// async global->LDS, 16 B/lane. LDS dest = wave-uniform base + lane*16.
__device__ __forceinline__ void lds16(const bf16* g, bf16* l) {
    __builtin_amdgcn_global_load_lds(
        (const __attribute__((address_space(1))) void*)g,
        (__attribute__((address_space(3))) void*)l, 16, 0, 0);
}

__device__ __forceinline__ float scrub(float f) {
    return (fabsf(f) < 1e30f) ? f : 0.f;   // NaN/Inf -> 0 (no-op valid data)
}

// T1 XCD-chunked swizzle for 2D GEMM grids (requires gx*gy % 8 == 0).
__device__ __forceinline__ void xcd_swizzle(int BMv, int BNv, int& mb, int& nb) {
    int gx = gridDim.x, gy = gridDim.y;
    int lin = blockIdx.y * gx + blockIdx.x;
    int q = (gx * gy) >> 3;
    lin = (lin & 7) * q + (lin >> 3);
    int mbi = lin / gy, nbi = lin - mbi * gy;
    mb = mbi * BMv; nb = nbi * BNv;
}

__global__ void sentinel_kernel(bf16* out) {
    out[threadIdx.x] = (bf16)1000.0f;
}

// ---------------------------------------------------------------------------
// prep: x convert + small-param converts + all 6 weight transposes, ONE launch
// ---------------------------------------------------------------------------
__global__ __launch_bounds__(256) void prep_kernel(
        const float* x,
        const float* wq, const float* wk, const float* wv, const float* wo,
        const float* w1, const float* w2,
        const float* bq, const float* bk, const float* bv, const float* bo,
        const float* b1, const float* b2,
        const float* l1a, const float* l1b, const float* l2a, const float* l2b,
        bf16* __restrict__ xcv,
        bf16* __restrict__ wT, bf16* __restrict__ w1T, bf16* __restrict__ w2T,
        bf16* __restrict__ prm) {
    __shared__ bf16 tile[32][33];
    int b = blockIdx.x;
    if (b < 4096) {
        int i = (b * 256 + threadIdx.x) * 4;
        float4 f = *(const float4*)(x + i);
        bf16x4 o = {(bf16)scrub(f.x), (bf16)scrub(f.y),
                    (bf16)scrub(f.z), (bf16)scrub(f.w)};
        *(bf16x4*)(xcv + i) = o;
        return;
    }
    if (b < 4106) {
        int pb = b - 4096;
        const float* srcs[10] = {bq, bk, bv, bo, b1, b2, l1a, l1b, l2a, l2b};
        const int len[10] = {512,512,512,512,2048,512,512,512,512,512};
        const int dst[10] = {0,512,1024,1536,2048,4096,4608,5120,5632,6144};
        const float* s = srcs[pb];
        bf16* d = prm + dst[pb];
        for (int i = threadIdx.x; i < len[pb]; i += 256)
            d[i] = (bf16)scrub(s[i]);
        return;
    }
    const float* in; bf16* out; int K, N, bx, by;
    if (b < 5130) {
        int idx = b - 4106, z = idx >> 8, rem = idx & 255;
        const float* srcs[4] = {wq, wk, wv, wo};
        in = srcs[z]; out = wT + (size_t)z * 262144;
        K = 512; N = 512; bx = rem & 15; by = rem >> 4;
    } else if (b < 6154) {
        int idx = b - 5130;
        in = w1; out = w1T; K = 512; N = 2048; bx = idx & 63; by = idx >> 6;
    } else {
        int idx = b - 6154;
        in = w2; out = w2T; K = 2048; N = 512; bx = idx & 15; by = idx >> 4;
    }
    int tx = threadIdx.x & 31, ty = threadIdx.x >> 5;
    int n0 = bx * 32, k0 = by * 32;
#pragma unroll
    for (int i = 0; i < 4; i++) {
        int kl = ty * 4 + i;
        tile[kl][tx] = (bf16)scrub(in[(size_t)(k0 + kl) * N + n0 + tx]);
    }
    __syncthreads();
#pragma unroll
    for (int i = 0; i < 4; i++) {
        int nl = ty * 4 + i;
        out[(size_t)(n0 + nl) * K + k0 + tx] = tile[tx][nl];
    }
}

// ---------------------------------------------------------------------------
// 128x128 GEMM, 2-phase stage-ahead pipeline over BK=32 slots. XCD-swizzled.
// r21-config FFN1 kernel (the 277.9us session-best configuration).
// ---------------------------------------------------------------------------
template <bool RELU>
__global__ __launch_bounds__(256) void gemm_bt(
        const bf16* __restrict__ A, const bf16* __restrict__ BT,
        const bf16* __restrict__ bias, bf16* __restrict__ Cout,
        int M, int N, int K) {
    constexpr int BM = 128, BN = 128;
    __shared__ __align__(16) bf16 As0[BM * 32], As1[BM * 32];
    __shared__ __align__(16) bf16 Bs0[BN * 32], Bs1[BN * 32];

    int tid  = threadIdx.x;
    int wid  = tid >> 6, lane = tid & 63;
    int quad = lane >> 4, l15 = lane & 15;
    int mb, nb;
    xcd_swizzle(BM, BN, mb, nb);
    int wm = (wid >> 1) * 64, wn = (wid & 1) * 64;

    f32x4 acc[4][4] = {};

    int c0 = wid * 128 + lane, c1 = c0 + 64;
    int ar0 = c0 >> 2, ac0 = (c0 & 3) * 8;
    int ar1 = c1 >> 2, ac1 = (c1 & 3) * 8;
    int o0 = wid * 1024, o1 = wid * 1024 + 512;

    lds16(&A [(size_t)(mb + ar0) * K + ac0], &As0[o0]);
    lds16(&A [(size_t)(mb + ar1) * K + ac1], &As0[o1]);
    lds16(&BT[(size_t)(nb + ar0) * K + ac0], &Bs0[o0]);
    lds16(&BT[(size_t)(nb + ar1) * K + ac1], &Bs0[o1]);
    __syncthreads();

    for (int k0 = 0; k0 < K; k0 += 64) {
        lds16(&A [(size_t)(mb + ar0) * K + k0 + 32 + ac0], &As1[o0]);
        lds16(&A [(size_t)(mb + ar1) * K + k0 + 32 + ac1], &As1[o1]);
        lds16(&BT[(size_t)(nb + ar0) * K + k0 + 32 + ac0], &Bs1[o0]);
        lds16(&BT[(size_t)(nb + ar1) * K + k0 + 32 + ac1], &Bs1[o1]);
        {
            bf16x8 af[4], bfr[4];
#pragma unroll
            for (int i = 0; i < 4; i++)
                af[i] = *(const bf16x8*)&As0[(wm + i * 16 + l15) * 32 + quad * 8];
#pragma unroll
            for (int j = 0; j < 4; j++)
                bfr[j] = *(const bf16x8*)&Bs0[(wn + j * 16 + l15) * 32 + quad * 8];
#pragma unroll
            for (int i = 0; i < 4; i++)
#pragma unroll
                for (int j = 0; j < 4; j++)
                    acc[i][j] = mfma16(af[i], bfr[j], acc[i][j]);
        }
        __syncthreads();
        if (k0 + 64 < K) {
            lds16(&A [(size_t)(mb + ar0) * K + k0 + 64 + ac0], &As0[o0]);
            lds16(&A [(size_t)(mb + ar1) * K + k0 + 64 + ac1], &As0[o1]);
            lds16(&BT[(size_t)(nb + ar0) * K + k0 + 64 + ac0], &Bs0[o0]);
            lds16(&BT[(size_t)(nb + ar1) * K + k0 + 64 + ac1], &Bs0[o1]);
        }
        {
            bf16x8 af[4], bfr[4];
#pragma unroll
            for (int i = 0; i < 4; i++)
                af[i] = *(const bf16x8*)&As1[(wm + i * 16 + l15) * 32 + quad * 8];
#pragma unroll
            for (int j = 0; j < 4; j++)
                bfr[j] = *(const bf16x8*)&Bs1[(wn + j * 16 + l15) * 32 + quad * 8];
#pragma unroll
            for (int i = 0; i < 4; i++)
#pragma unroll
                for (int j = 0; j < 4; j++)
                    acc[i][j] = mfma16(af[i], bfr[j], acc[i][j]);
        }
        __syncthreads();
    }

#pragma unroll
    for (int j = 0; j < 4; j++) {
        int n = nb + wn + j * 16 + l15;
        float bv = (float)bias[n];
#pragma unroll
        for (int i = 0; i < 4; i++) {
            int mBase = mb + wm + i * 16 + quad * 4;
#pragma unroll
            for (int r = 0; r < 4; r++) {
                float v = acc[i][j][r] + bv;
                if (RELU) v = v > 0.f ? v : 0.f;
                Cout[(size_t)(mBase + r) * N + n] = (bf16)v;
            }
        }
    }
}

// ---------------------------------------------------------------------------
// BM=64, BN=128 GEMM, 2-phase stage-ahead pipeline. For O-proj / FFN2.
// ---------------------------------------------------------------------------
template <bool RELU>
__global__ __launch_bounds__(256) void gemm_bt64(
        const bf16* __restrict__ A, const bf16* __restrict__ BT,
        const bf16* __restrict__ bias, bf16* __restrict__ Cout,
        int M, int N, int K) {
    constexpr int BM = 64, BN = 128;
    __shared__ __align__(16) bf16 As0[BM * 32], As1[BM * 32];
    __shared__ __align__(16) bf16 Bs0[BN * 32], Bs1[BN * 32];

    int tid  = threadIdx.x;
    int wid  = tid >> 6, lane = tid & 63;
    int quad = lane >> 4, l15 = lane & 15;
    int mb, nb;
    xcd_swizzle(BM, BN, mb, nb);
    int wm = (wid >> 1) * 32, wn = (wid & 1) * 64;

    f32x4 acc[2][4] = {};

    int cA = wid * 64 + lane;
    int arA = cA >> 2, acA = (cA & 3) * 8;
    int cB0 = wid * 128 + lane, cB1 = cB0 + 64;
    int br0 = cB0 >> 2, bc0 = (cB0 & 3) * 8;
    int br1 = cB1 >> 2, bc1 = (cB1 & 3) * 8;

    lds16(&A [(size_t)(mb + arA) * K + acA], &As0[wid * 512]);
    lds16(&BT[(size_t)(nb + br0) * K + bc0], &Bs0[wid * 1024]);
    lds16(&BT[(size_t)(nb + br1) * K + bc1], &Bs0[wid * 1024 + 512]);
    __syncthreads();

    for (int k0 = 0; k0 < K; k0 += 64) {
        lds16(&A [(size_t)(mb + arA) * K + k0 + 32 + acA], &As1[wid * 512]);
        lds16(&BT[(size_t)(nb + br0) * K + k0 + 32 + bc0], &Bs1[wid * 1024]);
        lds16(&BT[(size_t)(nb + br1) * K + k0 + 32 + bc1], &Bs1[wid * 1024 + 512]);
        {
            bf16x8 a0[2], b0[4];
#pragma unroll
            for (int i = 0; i < 2; i++)
                a0[i] = *(const bf16x8*)&As0[(wm + i * 16 + l15) * 32 + quad * 8];
#pragma unroll
            for (int j = 0; j < 4; j++)
                b0[j] = *(const bf16x8*)&Bs0[(wn + j * 16 + l15) * 32 + quad * 8];
#pragma unroll
            for (int i = 0; i < 2; i++)
#pragma unroll
                for (int j = 0; j < 4; j++)
                    acc[i][j] = mfma16(a0[i], b0[j], acc[i][j]);
        }
        __syncthreads();
        if (k0 + 64 < K) {
            lds16(&A [(size_t)(mb + arA) * K + k0 + 64 + acA], &As0[wid * 512]);
            lds16(&BT[(size_t)(nb + br0) * K + k0 + 64 + bc0], &Bs0[wid * 1024]);
            lds16(&BT[(size_t)(nb + br1) * K + k0 + 64 + bc1], &Bs0[wid * 1024 + 512]);
        }
        {
            bf16x8 a1[2], b1[4];
#pragma unroll
            for (int i = 0; i < 2; i++)
                a1[i] = *(const bf16x8*)&As1[(wm + i * 16 + l15) * 32 + quad * 8];
#pragma unroll
            for (int j = 0; j < 4; j++)
                b1[j] = *(const bf16x8*)&Bs1[(wn + j * 16 + l15) * 32 + quad * 8];
#pragma unroll
            for (int i = 0; i < 2; i++)
#pragma unroll
                for (int j = 0; j < 4; j++)
                    acc[i][j] = mfma16(a1[i], b1[j], acc[i][j]);
        }
        __syncthreads();
    }

#pragma unroll
    for (int j = 0; j < 4; j++) {
        int n = nb + wn + j * 16 + l15;
        float bv = (float)bias[n];
#pragma unroll
        for (int i = 0; i < 2; i++) {
            int mBase = mb + wm + i * 16 + quad * 4;
#pragma unroll
            for (int r = 0; r < 4; r++) {
                float v = acc[i][j][r] + bv;
                if (RELU) v = v > 0.f ? v : 0.f;
                Cout[(size_t)(mBase + r) * N + n] = (bf16)v;
            }
        }
    }
}

// ---------------------------------------------------------------------------
// Fused QKV GEMM, 2-phase stage-ahead pipeline; region 0 -> Q*(QSCALE),
// 1 -> K, 2 -> V^T via LDS-transposed coalesced epilogue. XCD-swizzled.
// ---------------------------------------------------------------------------
__global__ __launch_bounds__(256) void gemm_qkv(
        const bf16* __restrict__ A, const bf16* __restrict__ BT,
        const bf16* __restrict__ bias,
        bf16* __restrict__ Cq, bf16* __restrict__ Ck, bf16* __restrict__ Cv,
        int M, int N, int K) {
    constexpr int BM = 128, BN = 128;
    __shared__ __align__(16) bf16 As0[BM * 32], As1[BM * 32];
    __shared__ __align__(16) bf16 Bs0[BN * 32], Bs1[BN * 32];
    __shared__ __align__(16) bf16 Ts[128 * 136];

    int tid  = threadIdx.x;
    int wid  = tid >> 6, lane = tid & 63;
    int quad = lane >> 4, l15 = lane & 15;
    int mb, nb;
    xcd_swizzle(BM, BN, mb, nb);
    int wm = (wid >> 1) * 64, wn = (wid & 1) * 64;

    f32x4 acc[4][4] = {};

    int c0 = wid * 128 + lane, c1 = c0 + 64;
    int ar0 = c0 >> 2, ac0 = (c0 & 3) * 8;
    int ar1 = c1 >> 2, ac1 = (c1 & 3) * 8;
    int o0 = wid * 1024, o1 = wid * 1024 + 512;

    lds16(&A [(size_t)(mb + ar0) * K + ac0], &As0[o0]);
    lds16(&A [(size_t)(mb + ar1) * K + ac1], &As0[o1]);
    lds16(&BT[(size_t)(nb + ar0) * K + ac0], &Bs0[o0]);
    lds16(&BT[(size_t)(nb + ar1) * K + ac1], &Bs0[o1]);
    __syncthreads();

    for (int k0 = 0; k0 < K; k0 += 64) {
        lds16(&A [(size_t)(mb + ar0) * K + k0 + 32 + ac0], &As1[o0]);
        lds16(&A [(size_t)(mb + ar1) * K + k0 + 32 + ac1], &As1[o1]);
        lds16(&BT[(size_t)(nb + ar0) * K + k0 + 32 + ac0], &Bs1[o0]);
        lds16(&BT[(size_t)(nb + ar1) * K + k0 + 32 + ac1], &Bs1[o1]);
        {
            bf16x8 af[4], bfr[4];
#pragma unroll
            for (int i = 0; i < 4; i++)
                af[i] = *(const bf16x8*)&As0[(wm + i * 16 + l15) * 32 + quad * 8];
#pragma unroll
            for (int j = 0; j < 4; j++)
                bfr[j] = *(const bf16x8*)&Bs0[(wn + j * 16 + l15) * 32 + quad * 8];
#pragma unroll
            for (int i = 0; i < 4; i++)
#pragma unroll
                for (int j = 0; j < 4; j++)
                    acc[i][j] = mfma16(af[i], bfr[j], acc[i][j]);
        }
        __syncthreads();
        if (k0 + 64 < K) {
            lds16(&A [(size_t)(mb + ar0) * K + k0 + 64 + ac0], &As0[o0]);
            lds16(&A [(size_t)(mb + ar1) * K + k0 + 64 + ac1], &As0[o1]);
            lds16(&BT[(size_t)(nb + ar0) * K + k0 + 64 + ac0], &Bs0[o0]);
            lds16(&BT[(size_t)(nb + ar1) * K + k0 + 64 + ac1], &Bs0[o1]);
        }
        {
            bf16x8 af[4], bfr[4];
#pragma unroll
            for (int i = 0; i < 4; i++)
                af[i] = *(const bf16x8*)&As1[(wm + i * 16 + l15) * 32 + quad * 8];
#pragma unroll
            for (int j = 0; j < 4; j++)
                bfr[j] = *(const bf16x8*)&Bs1[(wn + j * 16 + l15) * 32 + quad * 8];
#pragma unroll
            for (int i = 0; i < 4; i++)
#pragma unroll
                for (int j = 0; j < 4; j++)
                    acc[i][j] = mfma16(af[i], bfr[j], acc[i][j]);
        }
        __syncthreads();
    }

    int reg = nb >> 9;   // 0=Q, 1=K, 2=V
    if (reg < 2) {
        bf16* C = reg ? Ck : Cq;
        float scl = reg ? 1.0f : QSCALE;
#pragma unroll
        for (int j = 0; j < 4; j++) {
            int n = nb + wn + j * 16 + l15;
            float bv = (float)bias[n];
            int nn = n & 511;
            int h = nn >> 6, dk = nn & 63;
#pragma unroll
            for (int i = 0; i < 4; i++) {
                int mBase = mb + wm + i * 16 + quad * 4;
#pragma unroll
                for (int r = 0; r < 4; r++) {
                    float v = (acc[i][j][r] + bv) * scl;
                    int m = mBase + r;
                    int b = m >> 11, s = m & (SEQ - 1);
                    C[((size_t)(b * NHEADS + h) * SEQ + s) * DHEAD + dk] = (bf16)v;
                }
            }
        }
    } else {
#pragma unroll
        for (int j = 0; j < 4; j++) {
            int nl = wn + j * 16 + l15;
            float bv = (float)bias[nb + nl];
#pragma unroll
            for (int i = 0; i < 4; i++) {
                int ml = wm + i * 16 + quad * 4;
                bf16x4 pk;
#pragma unroll
                for (int r = 0; r < 4; r++) pk[r] = (bf16)(acc[i][j][r] + bv);
                *(bf16x4*)&Ts[nl * 136 + ml] = pk;
            }
        }
        __syncthreads();
        int nl = tid >> 1, half = tid & 1;
        int nn = (nb + nl) & 511;
        int h = nn >> 6, dk = nn & 63;
        int bb = mb >> 11, s0 = mb & (SEQ - 1);
        bf16* dst = &Cv[((size_t)(bb * NHEADS + h) * DHEAD + dk) * SEQ + s0 + half * 64];
        const bf16* srcl = &Ts[nl * 136 + half * 64];
#pragma unroll
        for (int v = 0; v < 8; v++)
            *(uint4*)(dst + v * 8) = *(const uint4*)(srcl + v * 8);
    }
}

// ---------------------------------------------------------------------------
// Flash attention: grid (16, 32), block 256 = 4 waves, direct bf16 out.
// r27: KVBLK=128 -- two 64x64 sub-tiles per double buffer (identical
// r21/r22 swizzle per sub-tile), 16 steps; gload_lds staging with
// inverse-swizzled source; conflict-free frag reads; l-row via MFMA
// ones-trick; setprio around step compute; XCD swizzle.
// ---------------------------------------------------------------------------
__global__ __launch_bounds__(256) void attn_kernel(
        const bf16* __restrict__ Q, const bf16* __restrict__ K,
        const bf16* __restrict__ VT, bf16* __restrict__ Out) {
    __shared__ __align__(16) bf16 Ks[2][2][64 * 64];
    __shared__ __align__(16) bf16 Vs[2][2][64 * 64];
    __shared__ __align__(16) bf16 Pb[4][16 * 64];
    int tid  = threadIdx.x;
    int wid  = tid >> 6, lane = tid & 63;
    int quad = lane >> 4, l15 = lane & 15;

    int lin = blockIdx.y * 16 + blockIdx.x;        // grid is (16, 32)
    lin = (lin & 7) * 64 + (lin >> 3);             // bijective (512 = 8*64)
    int bh = lin >> 4;
    int qb = (lin & 15) * 128 + wid * 32;

    const bf16* Qh = Q  + (size_t)bh * SEQ * DHEAD;
    const bf16* Kh = K  + (size_t)bh * SEQ * DHEAD;
    const bf16* Vh = VT + (size_t)bh * DHEAD * SEQ;

    bf16x8 bQ0[2], bQ1[2];
#pragma unroll
    for (int c = 0; c < 2; c++) {
        const bf16* qp = &Qh[(qb + c * 16 + l15) * DHEAD + quad * 8];
        bQ0[c] = *(const bf16x8*)qp;
        bQ1[c] = *(const bf16x8*)(qp + 32);
    }

    bf16x8 vONE;
#pragma unroll
    for (int i = 0; i < 8; i++) vONE[i] = (bf16)1.0f;

    int srow = lane >> 3;
    int scol = ((lane & 7) ^ srow) << 3;   // global col offset (elems)
    int ldsb = wid * 1024;                 // wave's LDS base (elems)
    int krA = wid * 16 + srow, krB = krA + 8;

    int r7q = l15 & 7;
    int e0 = ((quad ^ r7q) << 3);
    int e1 = e0 ^ 32;

    f32x4 lacc[2] = {};
    f32x4 Oacc[2][4] = {};

    // prologue: stage 128-key tile 0 (both sub-tiles) into buffer 0
#pragma unroll
    for (int sb = 0; sb < 2; sb++) {
        lds16(&Kh[(size_t)(sb * 64 + krA) * DHEAD + scol], &Ks[0][sb][ldsb]);
        lds16(&Kh[(size_t)(sb * 64 + krB) * DHEAD + scol], &Ks[0][sb][ldsb + 512]);
        lds16(&Vh[(size_t)krA * SEQ + sb * 64 + scol],     &Vs[0][sb][ldsb]);
        lds16(&Vh[(size_t)krB * SEQ + sb * 64 + scol],     &Vs[0][sb][ldsb + 512]);
    }
    __syncthreads();

// one 64-key sub-tile compute body
#define ATTN_SUB(CUR, SB)                                                    \
    {                                                                        \
        bf16x8 aK0[4], aK1[4], bV0[4], bV1[4];                               \
        _Pragma("unroll")                                                    \
        for (int t = 0; t < 4; t++) {                                        \
            const bf16* kp = &Ks[CUR][SB][(t * 16 + l15) * 64];              \
            aK0[t] = *(const bf16x8*)(kp + e0);                              \
            aK1[t] = *(const bf16x8*)(kp + e1);                              \
            const bf16* vp = &Vs[CUR][SB][(t * 16 + l15) * 64];              \
            bV0[t] = *(const bf16x8*)(vp + e0);                              \
            bV1[t] = *(const bf16x8*)(vp + e1);                              \
        }                                                                    \
        _Pragma("unroll")                                                    \
        for (int c = 0; c < 2; c++) {                                        \
            f32x4 st[4];                                                     \
            _Pragma("unroll")                                                \
            for (int t = 0; t < 4; t++) {                                    \
                f32x4 zv = {0.f, 0.f, 0.f, 0.f};                             \
                st[t] = mfma16(aK1[t], bQ1[c], mfma16(aK0[t], bQ0[c], zv));  \
            }                                                                \
            bf16* myP = Pb[wid];                                             \
            _Pragma("unroll")                                                \
            for (int t = 0; t < 4; t++) {                                    \
                bf16x4 pk;                                                   \
                _Pragma("unroll")                                            \
                for (int r = 0; r < 4; r++)                                  \
                    pk[r] = (bf16)__builtin_amdgcn_exp2f(                    \
                                fminf(st[t][r], 60.f));                      \
                int pch = ((2 * t + (quad >> 1)) ^ r7q) << 3;                \
                *(bf16x4*)&myP[l15 * 64 + pch + ((quad & 1) << 2)] = pk;     \
            }                                                                \
            bf16x8 aP0 = *(const bf16x8*)&myP[l15 * 64 + e0];                \
            bf16x8 aP1 = *(const bf16x8*)&myP[l15 * 64 + e1];                \
            _Pragma("unroll")                                                \
            for (int nt = 0; nt < 4; nt++)                                   \
                Oacc[c][nt] = mfma16(aP1, bV1[nt],                           \
                                     mfma16(aP0, bV0[nt], Oacc[c][nt]));     \
            lacc[c] = mfma16(aP1, vONE, mfma16(aP0, vONE, lacc[c]));         \
        }                                                                    \
    }

// full 128-key step: prefetch next 128-key tile, compute both sub-tiles
#define ATTN_STEP(CUR, NXT, KB, PF)                                          \
    {                                                                        \
        if (PF) {                                                            \
            _Pragma("unroll")                                                \
            for (int sb = 0; sb < 2; sb++) {                                 \
                lds16(&Kh[(size_t)((KB) + sb * 64 + krA) * DHEAD + scol],    \
                      &Ks[NXT][sb][ldsb]);                                   \
                lds16(&Kh[(size_t)((KB) + sb * 64 + krB) * DHEAD + scol],    \
                      &Ks[NXT][sb][ldsb + 512]);                             \
                lds16(&Vh[(size_t)krA * SEQ + (KB) + sb * 64 + scol],        \
                      &Vs[NXT][sb][ldsb]);                                   \
                lds16(&Vh[(size_t)krB * SEQ + (KB) + sb * 64 + scol],        \
                      &Vs[NXT][sb][ldsb + 512]);                             \
            }                                                                \
        }                                                                    \
        __builtin_amdgcn_s_setprio(1);                                       \
        ATTN_SUB(CUR, 0);                                                    \
        ATTN_SUB(CUR, 1);                                                    \
        __builtin_amdgcn_s_setprio(0);                                       \
        __syncthreads();                                                     \
    }

    for (int it2 = 0; it2 < SEQ / 256; it2++) {
        ATTN_STEP(0, 1, (2 * it2 + 1) * 128, true);
        ATTN_STEP(1, 0, (2 * it2 + 2) * 128, (it2 + 1 < SEQ / 256));
    }
#undef ATTN_STEP
#undef ATTN_SUB

    int b = bh >> 3, hd = bh & 7;
#pragma unroll
    for (int c = 0; c < 2; c++) {
        float linv[4];
#pragma unroll
        for (int r = 0; r < 4; r++)
            linv[r] = 1.f / lacc[c][r];
#pragma unroll
        for (int nt = 0; nt < 4; nt++)
#pragma unroll
            for (int r = 0; r < 4; r++) {
                int s = qb + c * 16 + quad * 4 + r;
                Out[((size_t)(b * SEQ + s)) * DMODEL + hd * 64 + nt * 16 + l15]
                    = (bf16)(Oacc[c][nt][r] * linv[r]);
            }
    }
}

// ---------------------------------------------------------------------------
// Residual + LayerNorm (unbiased std ddof=1, eps added to std).
// ---------------------------------------------------------------------------
__global__ __launch_bounds__(256) void ln_kernel(
        const bf16* __restrict__ X, const bf16* __restrict__ T,
        const bf16* __restrict__ Al, const bf16* __restrict__ Bl,
        void* __restrict__ Out, int final_out) {
    int wid = threadIdx.x >> 6, lane = threadIdx.x & 63;
    int row = blockIdx.x * 4 + wid;
    const bf16* xr = X + (size_t)row * DMODEL;
    const bf16* tr = T + (size_t)row * DMODEL;
    bf16x8 xv = *(const bf16x8*)&xr[lane * 8];
    bf16x8 tv = *(const bf16x8*)&tr[lane * 8];
    float v[8];
#pragma unroll
    for (int i = 0; i < 8; i++) v[i] = (float)xv[i] + (float)tv[i];
    float sum = 0.f, sq = 0.f;
#pragma unroll
    for (int i = 0; i < 8; i++) { sum += v[i]; sq += v[i] * v[i]; }
#pragma unroll
    for (int m = 1; m < 64; m <<= 1) {
        sum += __shfl_xor(sum, m);
        sq  += __shfl_xor(sq,  m);
    }
    float mean = sum * (1.f / DMODEL);
    float var  = (sq - DMODEL * mean * mean) * (1.f / (DMODEL - 1));
    var = var > 0.f ? var : 0.f;
    float inv = 1.f / (sqrtf(var) + 1e-6f);
#pragma unroll
    for (int i = 0; i < 8; i++) {
        int c = lane * 8 + i;
        float yv = (float)Al[c] * (v[i] - mean) * inv + (float)Bl[c];
        yv = fminf(fmaxf(yv, -1e4f), 1e4f);
        size_t idx = (size_t)row * DMODEL + c;
        if (final_out) ((float*)Out)[idx] = yv;
        else           ((bf16*)Out)[idx]  = (bf16)yv;
    }
}

// ---------------------------------------------------------------------------
extern "C" void kernel_launch(void* const* d_in, const int* in_sizes, int n_in,
                              void* d_out, int out_size, void* d_ws, size_t ws_size,
                              hipStream_t stream) {
    if (ws_size < WS_NEED) {
        sentinel_kernel<<<1, 64, 0, stream>>>((bf16*)d_out);
        return;
    }

    const float* x  = (const float*)d_in[0];
    const float* wq = (const float*)d_in[1],  *bq = (const float*)d_in[2];
    const float* wk = (const float*)d_in[3],  *bk = (const float*)d_in[4];
    const float* wv = (const float*)d_in[5],  *bv = (const float*)d_in[6];
    const float* wo = (const float*)d_in[7],  *bo = (const float*)d_in[8];
    const float* w1 = (const float*)d_in[9],  *b1 = (const float*)d_in[10];
    const float* w2 = (const float*)d_in[11], *b2 = (const float*)d_in[12];
    const float* ln1a = (const float*)d_in[13], *ln1b = (const float*)d_in[14];
    const float* ln2a = (const float*)d_in[15], *ln2b = (const float*)d_in[16];

    char* ws = (char*)d_ws;
    bf16* wT   = (bf16*)(ws + 0);
    bf16* woT  = (bf16*)(ws + 1572864);
    bf16* w1T  = (bf16*)(ws + 2097152);
    bf16* w2T  = (bf16*)(ws + 4194304);
    bf16* xcv  = (bf16*)(ws + 6291456);
    bf16* prm  = (bf16*)(ws + 14680064);
    bf16* regA = (bf16*)(ws + 14696448);
    bf16* regB = (bf16*)(ws + 23085056);
    bf16* regC = (bf16*)(ws + 31473664);
    bf16* ff1  = (bf16*)(ws + 39862272);
    bf16* aout = (bf16*)d_out;   // scratch (fully overwritten by final LN)

    bf16 *pbq = prm, *pbo = prm + 1536;
    bf16 *pb1 = prm + 2048, *pb2 = prm + 4096;
    bf16 *pl1a = prm + 4608, *pl1b = prm + 5120;
    bf16 *pl2a = prm + 5632, *pl2b = prm + 6144;

    prep_kernel<<<7178, 256, 0, stream>>>(x, wq, wk, wv, wo, w1, w2,
                                          bq, bk, bv, bo, b1, b2,
                                          ln1a, ln1b, ln2a, ln2b,
                                          xcv, wT, w1T, w2T, prm);

    // fused QKV projection (Q pre-scaled by QSCALE; V^T coalesced epilogue)
    gemm_qkv<<<dim3(64, 12), 256, 0, stream>>>(xcv, wT, pbq,
                                               regA, regB, regC,
                                               MTOT, 3 * DMODEL, DMODEL);

    // attention -> d_out (scratch), direct bf16
    attn_kernel<<<dim3(SEQ / 128, NBATCH * NHEADS), 256, 0, stream>>>(
        regA, regB, regC, aout);

    // O-proj: aout -> t (regA); BM=64/BK=64
    gemm_bt64<false><<<dim3(128, 4), 256, 0, stream>>>(aout, woT, pbo, regA,
                                                       MTOT, DMODEL, DMODEL);

    // LN1: xcv + t -> y (regB)
    ln_kernel<<<MTOT / 4, 256, 0, stream>>>(xcv, regA, pl1a, pl1b, regB, 0);

    // FFN1: y -> ff1 (ReLU), 128^2 2-phase (r21 session-best config)
    gemm_bt<true><<<dim3(64, 16), 256, 0, stream>>>(regB, w1T, pb1, ff1,
                                                    MTOT, DFF, DMODEL);

    // FFN2: ff1 -> ff2 (regA)
    gemm_bt64<false><<<dim3(128, 4), 256, 0, stream>>>(ff1, w2T, pb2, regA,
                                                       MTOT, DMODEL, DFF);

    // LN2: y + ff2 -> out (fp32)
    ln_kernel<<<MTOT / 4, 256, 0, stream>>>(regB, regA, pl2a, pl2b, d_out, 1);
}